// Round 10
// baseline (3357.592 us; speedup 1.0000x reference)
//
#include <hip/hip_runtime.h>

#define TPB 256
#define MAXJ 48

// role bases
#define SC_N 128
#define YD0 128  // 32 WGs
#define YU0 160  // 7
#define WD0 167  // 8
#define WU0 175  // 7
#define DT0 182  // 16
#define XP0 198  // 32
#define XR0 230  // 16
#define U0 246   // 8
#define NWG 254
#define NGRP 8
#define GCH 32

// ---------------------------------------------------------------------------
// Coherent (agent-scope, MALL-served) helpers: sc1 loads/stores, no fences.
// ---------------------------------------------------------------------------
__device__ __forceinline__ void cst(float* p, float v) {
  __hip_atomic_store(p, v, __ATOMIC_RELAXED, __HIP_MEMORY_SCOPE_AGENT);
}
__device__ __forceinline__ void cstu(unsigned* p, unsigned v) {
  __hip_atomic_store(p, v, __ATOMIC_RELAXED, __HIP_MEMORY_SCOPE_AGENT);
}
__device__ __forceinline__ unsigned cldu(const unsigned* p) {
  return __hip_atomic_load(p, __ATOMIC_RELAXED, __HIP_MEMORY_SCOPE_AGENT);
}
__device__ __forceinline__ float cld(const float* p) {
  return __hip_atomic_load(p, __ATOMIC_RELAXED, __HIP_MEMORY_SCOPE_AGENT);
}
__device__ __forceinline__ float2 cld2(const float* p) {
  unsigned long long u = __hip_atomic_load(
      reinterpret_cast<const unsigned long long*>(p), __ATOMIC_RELAXED,
      __HIP_MEMORY_SCOPE_AGENT);
  float2 v;
  __builtin_memcpy(&v, &u, 8);
  return v;
}

// ---------------------------------------------------------------------------
// Hierarchical grid barrier: arrival flag/WG, 8 checkers, 8 group flags.
// ---------------------------------------------------------------------------
__device__ __forceinline__ void grid_barrier(unsigned* __restrict__ arr,
                                             unsigned* __restrict__ grp,
                                             int bid, int tid, unsigned phase) {
  asm volatile("s_waitcnt vmcnt(0)" ::: "memory");
  __syncthreads();
  if (tid == 0) cstu(arr + (bid << 5), phase);
  if (bid < NGRP) {
    const int lo = bid * GCH;
    const int n = (NWG - lo < GCH) ? (NWG - lo) : GCH;
    if (tid < n) {
      while (cldu(arr + ((lo + tid) << 5)) < phase) __builtin_amdgcn_s_sleep(1);
    }
    __syncthreads();
    if (tid == 0) cstu(grp + (bid << 5), phase);
  }
  if (tid < NGRP) {
    while (cldu(grp + (tid << 5)) < phase) __builtin_amdgcn_s_sleep(1);
  }
  __atomic_signal_fence(__ATOMIC_SEQ_CST);
  __syncthreads();
}

// ---------------------------------------------------------------------------
// Tiled fp32 GEMM tile body.
// ---------------------------------------------------------------------------
__device__ void gemm_tile(const float* __restrict__ X, const float* __restrict__ Y,
                          float* __restrict__ Z, int M, int N, int Kd,
                          int mtile, int ntile) {
  __shared__ float Xs[16][65];
  __shared__ float Ys[16][65];
  const int tx = threadIdx.x & 15;
  const int ty = threadIdx.x >> 4;
  const int mbase = mtile * 64;
  const int nbase = ntile * 64;
  float acc[4][4] = {};
  for (int k0 = 0; k0 < Kd; k0 += 16) {
#pragma unroll
    for (int r = 0; r < 4; ++r) {
      int idx = threadIdx.x + 256 * r;
      int mm = idx >> 4, kk = idx & 15;
      int gm = mbase + mm, gk = k0 + kk;
      Xs[kk][mm] = (gm < M && gk < Kd) ? X[(size_t)gm * Kd + gk] : 0.f;
      int nn = idx & 63, k2 = idx >> 6;
      int gn = nbase + nn, gk2 = k0 + k2;
      Ys[k2][nn] = (gk2 < Kd && gn < N) ? Y[(size_t)gk2 * N + gn] : 0.f;
    }
    __syncthreads();
#pragma unroll
    for (int kk = 0; kk < 16; ++kk) {
      float xv[4], yv[4];
#pragma unroll
      for (int a = 0; a < 4; ++a) xv[a] = Xs[kk][ty * 4 + a];
#pragma unroll
      for (int b = 0; b < 4; ++b) yv[b] = Ys[kk][tx * 4 + b];
#pragma unroll
      for (int a = 0; a < 4; ++a)
#pragma unroll
        for (int b = 0; b < 4; ++b) acc[a][b] += xv[a] * yv[b];
    }
    __syncthreads();
  }
#pragma unroll
  for (int a = 0; a < 4; ++a) {
    int gm = mbase + ty * 4 + a;
    if (gm < M) {
#pragma unroll
      for (int b = 0; b < 4; ++b) {
        int gn = nbase + tx * 4 + b;
        if (gn < N) Z[(size_t)gm * N + gn] = acc[a][b];
      }
    }
  }
}

struct JobBatch {
  int n;
  int start[MAXJ + 1];
  int xsel[MAXJ], xoff[MAXJ], ysel[MAXJ], yoff[MAXJ], zoff[MAXJ];
  int M[MAXJ], N[MAXJ], K[MAXJ];
};

__global__ __launch_bounds__(256) void multi_gemm(JobBatch jb,
    const float* __restrict__ A, const float* __restrict__ Bm,
    const float* __restrict__ C, const float* __restrict__ Km,
    float* __restrict__ ws) {
  int b = blockIdx.x;
  int j = 0;
  while (j < jb.n - 1 && b >= jb.start[j + 1]) ++j;
  int rel = b - jb.start[j];
  const float* bases[5] = {ws, A, Bm, C, Km};
  const float* X = bases[jb.xsel[j]] + jb.xoff[j];
  const float* Y = bases[jb.ysel[j]] + jb.yoff[j];
  float* Z = ws + jb.zoff[j];
  int tn = jb.N[j] >> 6;
  gemm_tile(X, Y, Z, jb.M[j], jb.N[j], jb.K[j], rel / tn, rel % tn);
}

// ---------------------------------------------------------------------------
__global__ __launch_bounds__(256) void m2_kernel(const float* __restrict__ MT,
    const float* __restrict__ sm, float* __restrict__ M2g) {
  int idx = blockIdx.x * 256 + threadIdx.x;
  if (idx >= 128 * 32 * 256) return;
  int q = idx & 255;
  int ci = idx >> 8;
  const float* base = MT + (size_t)ci * 32 * 256 + q;
  float acc = 0.f;
#pragma unroll
  for (int j = 0; j < 32; ++j) acc += base[j * 256] * sm[j];
  M2g[idx] = acc;
}

__global__ __launch_bounds__(256) void wfir_kernel(const float* __restrict__ M2g,
    const float* __restrict__ Phi, float* __restrict__ W) {
  int idx = blockIdx.x * 256 + threadIdx.x;  // j*32768 + c*256 + q
  if (idx >= 64 * 32768) return;
  int j = idx >> 15;
  int cq = idx & 32767;
  int c = cq >> 8;
  int q = cq & 255;
  float acc = 0.f;
#pragma unroll
  for (int i = 0; i < 32; ++i)
    acc = fmaf(Phi[(i << 6) | j], M2g[(size_t)(((c << 5) | i) << 8) | q], acc);
  W[idx] = acc;
}

__global__ __launch_bounds__(256) void axpy_acl(const float* __restrict__ A,
    const float* __restrict__ BKC, float* __restrict__ Acl, float* __restrict__ P1) {
  int i = blockIdx.x * 256 + threadIdx.x;
  if (i < 262144) {
    float v = A[i] - BKC[i];
    Acl[i] = v;
    P1[i] = v;
  }
}

// ---------------------------------------------------------------------------
__global__ void init_kernel(const float* __restrict__ x0, float* __restrict__ xh,
    float* __restrict__ eh, float* __restrict__ ynh, float* __restrict__ uh0,
    float* __restrict__ dbnd, unsigned* __restrict__ arr,
    unsigned* __restrict__ grp) {
  int i = blockIdx.x * 256 + threadIdx.x;
  int stride = gridDim.x * 256;
  for (int k = i; k < 524288; k += stride) cst(xh + k, 0.f);
  for (int k = i; k < 139264; k += stride) cst(eh + k, 0.f);
  for (int k = i; k < 262144; k += stride) cst(ynh + k, 0.f);
  for (int k = i; k < 8192; k += stride) cst(uh0 + k, 0.f);
  for (int k = i; k < NWG * 32; k += stride) cstu(arr + k, 0u);
  for (int k = i; k < NGRP * 32; k += stride) cstu(grp + k, 0u);
  if (i < 512) cst(dbnd + i, x0[i]);
}

// ---------------------------------------------------------------------------
// Persistent main loop: 131 phases x ONE barrier. T=8*ph. Lag schedule:
//   SC (0..127)  : e[Ty+r] += W[r-s]·y[Ty+s], Ty=T-8
//   Yd (128..159): y[T+s] += CA[s] d_T           (s=r>>2, 64-row quarter)
//   Yu (160..166): y[T+s] += sum_m CAB33[m] u[..]  (loop-swapped, acc[8])
//   Wd (167..174): e[T+s] += W0CA[s] d_T
//   Wu (175..181): e[T+s] += sum_m W0CAB33[m] u[..] (loop-swapped)
//   Dt (182..197): dbnd[ph+1] = A8 d_T + sum AB33[m] u[..]
//   Xp (198..229): x[Tq+s] += P[s+1] x[Tq-1], Tq=T-16
//   Xr (230..245): x[Tq+s] += sum_i Rn[i] e[Tq+s-1-i]  (loop-swapped)
//   U  (246..253): u[Tu+s] = e[Tu+s] - KC x[Tu+s], Tu=T-24
// Loop-swap: map element loaded ONCE per phase (acc[8] in regs) -> per-WG
// L2 stream <= 256 KB/phase (was up to 1 MB with per-s reload).
// ---------------------------------------------------------------------------
__global__ __launch_bounds__(TPB, 1) void main_kernel(
    const float* __restrict__ B, const float* __restrict__ C,
    const float* __restrict__ x0, const float* __restrict__ Wfir,
    const float* __restrict__ KC, const float* __restrict__ W0C,
    const float* __restrict__ Pp, const float* __restrict__ CAp,
    const float* __restrict__ W0CAp, const float* __restrict__ Rnp,
    const float* __restrict__ AB33p, const float* __restrict__ CAB33p,
    const float* __restrict__ W0CAB33p, const float* __restrict__ A8k,
    float* __restrict__ xh, float* __restrict__ uh0, float* __restrict__ eh,
    float* __restrict__ ynh, float* __restrict__ dbnd,
    unsigned* __restrict__ arr, unsigned* __restrict__ grp) {
  __shared__ float smA[64 * 256];
  __shared__ float smY[8 * 256];
  __shared__ float smV[512];
  __shared__ float smW[8 * 128];
  __shared__ float smVx[8 * 516];
  __shared__ float redsc[4][16];
  const int bid = blockIdx.x;
  const int tid = threadIdx.x;

  if (bid < SC_N) {
    // ================= SC =================
    for (int i = tid; i < 16384; i += TPB) {
      int j = i >> 8;
      smA[i] = (j >= 1) ? Wfir[(size_t)j * 32768 + bid * 256 + (i & 255)] : 0.f;
    }
    __syncthreads();
#pragma unroll 1
    for (int ph = 0; ph <= 130; ++ph) {
      if (ph >= 1 && ph < 129) {
        const int Ty = ph * 8 - 8;
        for (int i2 = tid; i2 < 1024; i2 += TPB) {
          float2 v = cld2(ynh + (size_t)Ty * 256 + 2 * i2);
          smY[2 * i2] = v.x;
          smY[2 * i2 + 1] = v.y;
        }
        __syncthreads();
        const int q = tid;
        float yreg[8];
#pragma unroll
        for (int s = 0; s < 8; ++s) yreg[s] = smY[s * 256 + q];
        const int wv = tid >> 6;
        const int lane = tid & 63;
#pragma unroll
        for (int kt = 0; kt < 5; ++kt) {
          const int r0 = 1 + 16 * kt;
          float wreg[23];
#pragma unroll
          for (int i = 0; i < 23; ++i) {
            const int j = r0 - 7 + i;
            wreg[i] = (j >= 1 && j <= 63) ? smA[j * 256 + q] : 0.f;
          }
          float acc[16];
#pragma unroll
          for (int a = 0; a < 16; ++a) acc[a] = 0.f;
#pragma unroll
          for (int a = 0; a < 16; ++a)
#pragma unroll
            for (int s = 0; s < 8; ++s) acc[a] += wreg[a + 7 - s] * yreg[s];
#pragma unroll
          for (int a = 0; a < 16; ++a) {
            float v = acc[a];
            v += __shfl_xor(v, 32);
            v += __shfl_xor(v, 16);
            v += __shfl_xor(v, 8);
            v += __shfl_xor(v, 4);
            v += __shfl_xor(v, 2);
            v += __shfl_xor(v, 1);
            if (lane == 0) redsc[wv][a] = v;
          }
          __syncthreads();
          if (tid < 16) {
            const int r = r0 + tid;
            if (r <= 70) {
              float sum = redsc[0][tid] + redsc[1][tid] + redsc[2][tid] + redsc[3][tid];
              atomicAdd(&eh[(size_t)(Ty + r) * 128 + bid], sum);
            }
          }
          __syncthreads();
        }
      }
      grid_barrier(arr, grp, bid, tid, (unsigned)(ph + 1));
    }
  } else if (bid < YU0) {
    // ================= Yd ================= (32 WGs, 4-lane split)
    const int r = bid - YD0;
    const int s = r >> 2;
    const int qtr = (r & 3) * 64;
    const int row = qtr + (tid >> 2);
    const int ks = (tid & 3) * 128;
    const float* Mrow = (s == 0) ? C : (CAp + (size_t)(s - 1) * 131072);
    const float4* m4 = (const float4*)(Mrow + (size_t)row * 512 + ks);
#pragma unroll 1
    for (int ph = 0; ph <= 130; ++ph) {
      if (ph < 128) {
        const int T = ph * 8;
        {
          float2 v = cld2(dbnd + (size_t)ph * 512 + 2 * tid);
          smV[2 * tid] = v.x;
          smV[2 * tid + 1] = v.y;
        }
        __syncthreads();
        const float4* v4 = (const float4*)(smV + ks);
        float a = 0.f;
#pragma unroll
        for (int it = 0; it < 32; ++it) {
          float4 mm = m4[it], vv = v4[it];
          a += mm.x * vv.x + mm.y * vv.y + mm.z * vv.z + mm.w * vv.w;
        }
        a += __shfl_down(a, 2);
        a += __shfl_down(a, 1);
        if ((tid & 3) == 0) atomicAdd(&ynh[(size_t)(T + s) * 256 + row], a);
      }
      grid_barrier(arr, grp, bid, tid, (unsigned)(ph + 1));
    }
  } else if (bid < WD0) {
    // ================= Yu ================= (7 WGs, loop-swapped)
    const int m = bid - YU0;
    const int row = tid;
    const float4* m4 = (const float4*)(CAB33p + (size_t)m * 32768 + (size_t)row * 128);
#pragma unroll 1
    for (int ph = 0; ph <= 130; ++ph) {
      if (ph < 128) {
        const int T = ph * 8;
        for (int i2 = tid; i2 < 512; i2 += TPB) {
          float2 v = cld2(uh0 + (size_t)(64 + T - 33) * 128 + 2 * i2);
          smW[2 * i2] = v.x;
          smW[2 * i2 + 1] = v.y;
        }
        __syncthreads();
        float acc[8];
#pragma unroll
        for (int s = 0; s < 8; ++s) acc[s] = 0.f;
#pragma unroll 4
        for (int it = 0; it < 32; ++it) {
          float4 mm = m4[it];
#pragma unroll
          for (int s = 0; s < 8; ++s) {
            if (s > m) {
              float4 vv = ((const float4*)(smW + (s - m - 1) * 128))[it];
              acc[s] += mm.x * vv.x + mm.y * vv.y + mm.z * vv.z + mm.w * vv.w;
            }
          }
        }
#pragma unroll
        for (int s = 0; s < 8; ++s)
          if (s > m) atomicAdd(&ynh[(size_t)(T + s) * 256 + row], acc[s]);
      }
      grid_barrier(arr, grp, bid, tid, (unsigned)(ph + 1));
    }
  } else if (bid < WU0) {
    // ================= Wd ================= (8 WGs)
    const int s = bid - WD0;
    const int row = tid >> 1;
    const int seg = tid & 1;
    const float* Mrow = (s == 0) ? W0C : (W0CAp + (size_t)(s - 1) * 65536);
    const float4* m4 = (const float4*)(Mrow + (size_t)row * 512 + seg * 256);
#pragma unroll 1
    for (int ph = 0; ph <= 130; ++ph) {
      if (ph < 128) {
        const int T = ph * 8;
        {
          float2 v = cld2(dbnd + (size_t)ph * 512 + 2 * tid);
          smV[2 * tid] = v.x;
          smV[2 * tid + 1] = v.y;
        }
        __syncthreads();
        const float4* v4 = (const float4*)(smV + seg * 256);
        float a = 0.f;
#pragma unroll
        for (int it = 0; it < 64; ++it) {
          float4 mm = m4[it], vv = v4[it];
          a += mm.x * vv.x + mm.y * vv.y + mm.z * vv.z + mm.w * vv.w;
        }
        a += __shfl_down(a, 1);
        if (seg == 0) atomicAdd(&eh[(size_t)(T + s) * 128 + row], a);
      }
      grid_barrier(arr, grp, bid, tid, (unsigned)(ph + 1));
    }
  } else if (bid < DT0) {
    // ================= Wu ================= (7 WGs, loop-swapped)
    const int m = bid - WU0;
    const int row = tid >> 1;
    const int seg = tid & 1;
    const float4* m4 = (const float4*)(W0CAB33p + (size_t)m * 16384 + (size_t)row * 128 + seg * 64);
#pragma unroll 1
    for (int ph = 0; ph <= 130; ++ph) {
      if (ph < 128) {
        const int T = ph * 8;
        for (int i2 = tid; i2 < 512; i2 += TPB) {
          float2 v = cld2(uh0 + (size_t)(64 + T - 33) * 128 + 2 * i2);
          smW[2 * i2] = v.x;
          smW[2 * i2 + 1] = v.y;
        }
        __syncthreads();
        float acc[8];
#pragma unroll
        for (int s = 0; s < 8; ++s) acc[s] = 0.f;
#pragma unroll 4
        for (int it = 0; it < 16; ++it) {
          float4 mm = m4[it];
#pragma unroll
          for (int s = 0; s < 8; ++s) {
            if (s > m) {
              float4 vv = ((const float4*)(smW + (s - m - 1) * 128 + seg * 64))[it];
              acc[s] += mm.x * vv.x + mm.y * vv.y + mm.z * vv.z + mm.w * vv.w;
            }
          }
        }
#pragma unroll
        for (int s = 0; s < 8; ++s) {
          if (s > m) {
            float v = acc[s];
            v += __shfl_down(v, 1);
            if (seg == 0) atomicAdd(&eh[(size_t)(T + s) * 128 + row], v);
          }
        }
      }
      grid_barrier(arr, grp, bid, tid, (unsigned)(ph + 1));
    }
  } else if (bid < XP0) {
    // ================= Dt ================= (16 WGs)
    const int g = bid - DT0;
    const int row = g * 32 + (tid >> 3);
    const int l8 = tid & 7;
#pragma unroll 1
    for (int ph = 0; ph <= 130; ++ph) {
      if (ph < 127) {
        const int T = ph * 8;
        {
          float2 v = cld2(dbnd + (size_t)ph * 512 + 2 * tid);
          smV[2 * tid] = v.x;
          smV[2 * tid + 1] = v.y;
        }
        for (int i2 = tid; i2 < 512; i2 += TPB) {
          float2 v = cld2(uh0 + (size_t)(64 + T - 33) * 128 + 2 * i2);
          smW[2 * i2] = v.x;
          smW[2 * i2 + 1] = v.y;
        }
        __syncthreads();
        float a = 0.f;
        {
          const float4* m4 = (const float4*)(A8k + (size_t)row * 512 + l8 * 64);
          const float4* v4 = (const float4*)(smV + l8 * 64);
#pragma unroll
          for (int it = 0; it < 16; ++it) {
            float4 mm = m4[it], vv = v4[it];
            a += mm.x * vv.x + mm.y * vv.y + mm.z * vv.z + mm.w * vv.w;
          }
        }
#pragma unroll
        for (int m = 0; m < 8; ++m) {
          const float4* m4 = (const float4*)(AB33p + (size_t)m * 65536 + (size_t)row * 128 + l8 * 16);
          const float4* v4 = (const float4*)(smW + (7 - m) * 128 + l8 * 16);
#pragma unroll
          for (int it = 0; it < 4; ++it) {
            float4 mm = m4[it], vv = v4[it];
            a += mm.x * vv.x + mm.y * vv.y + mm.z * vv.z + mm.w * vv.w;
          }
        }
        a += __shfl_down(a, 4);
        a += __shfl_down(a, 2);
        a += __shfl_down(a, 1);
        if (l8 == 0) cst(&dbnd[(size_t)(ph + 1) * 512 + row], a);
      }
      grid_barrier(arr, grp, bid, tid, (unsigned)(ph + 1));
    }
  } else if (bid < XR0) {
    // ================= Xp ================= (32 WGs)
    const int r = bid - XP0;
    const int s = r >> 2;
    const int qtr = (r & 3) << 7;
    const int row = qtr + (tid >> 1);
    const int seg = tid & 1;
#pragma unroll 1
    for (int ph = 0; ph <= 130; ++ph) {
      if (ph >= 2 && ph < 130) {
        const int Tq = ph * 8 - 16;
        {
          const float* src = (ph == 2) ? x0 : (xh + (size_t)(Tq - 1) * 512);
          float2 v = cld2(src + 2 * tid);
          smV[2 * tid] = v.x;
          smV[2 * tid + 1] = v.y;
        }
        __syncthreads();
        const int pslot = (ph == 2) ? s : (s + 1);
        if (pslot == 0) {
          if (seg == 0) atomicAdd(&xh[(size_t)Tq * 512 + row], smV[row]);
        } else {
          const float4* m4 = (const float4*)(Pp + (size_t)(pslot - 1) * 262144 +
                                             (size_t)row * 512 + seg * 256);
          const float4* v4 = (const float4*)(smV + seg * 256);
          float a = 0.f;
#pragma unroll
          for (int it = 0; it < 64; ++it) {
            float4 mm = m4[it], vv = v4[it];
            a += mm.x * vv.x + mm.y * vv.y + mm.z * vv.z + mm.w * vv.w;
          }
          a += __shfl_down(a, 1);
          if (seg == 0) atomicAdd(&xh[(size_t)(Tq + s) * 512 + row], a);
        }
      }
      grid_barrier(arr, grp, bid, tid, (unsigned)(ph + 1));
    }
  } else if (bid < U0) {
    // ================= Xr ================= (16 WGs, loop-swapped)
    const int r = bid - XR0;
    const int i = r >> 1;
    const int half = (r & 1) << 8;
    const int row = half + tid;
    const float* Rrow = (i == 0) ? (B + (size_t)row * 128)
                                 : (Rnp + (size_t)(i - 1) * 65536 + (size_t)row * 128);
    const float4* m4 = (const float4*)Rrow;
#pragma unroll 1
    for (int ph = 0; ph <= 130; ++ph) {
      if (ph >= 2 && ph < 130) {
        const int Tq = ph * 8 - 16;
        for (int i2 = tid; i2 < 512; i2 += TPB) {
          int idx = 2 * i2;
          float2 v;
          if (ph == 2 && idx < 128) {
            v.x = 0.f;
            v.y = 0.f;
          } else {
            v = cld2(eh + (size_t)(Tq - 1) * 128 + idx);
          }
          smW[idx] = v.x;
          smW[idx + 1] = v.y;
        }
        __syncthreads();
        float acc[8];
#pragma unroll
        for (int s = 0; s < 8; ++s) acc[s] = 0.f;
#pragma unroll 4
        for (int it = 0; it < 32; ++it) {
          float4 mm = m4[it];
#pragma unroll
          for (int s = 0; s < 8; ++s) {
            if (s >= i) {
              float4 vv = ((const float4*)(smW + (s - i) * 128))[it];
              acc[s] += mm.x * vv.x + mm.y * vv.y + mm.z * vv.z + mm.w * vv.w;
            }
          }
        }
#pragma unroll
        for (int s = 0; s < 8; ++s)
          if (s >= i) atomicAdd(&xh[(size_t)(Tq + s) * 512 + row], acc[s]);
      }
      grid_barrier(arr, grp, bid, tid, (unsigned)(ph + 1));
    }
  } else {
    // ================= U ================= (8 WGs)
    const int g = bid - U0;
    const int o = tid >> 1;
    const int par = tid & 1;
    const int s = o >> 4;
    const int lr = o & 15;
    const int row = g * 16 + lr;
    const float4* m4 = (const float4*)(KC + (size_t)row * 512 + par * 256);
#pragma unroll 1
    for (int ph = 0; ph <= 130; ++ph) {
      if (ph >= 3) {
        const int Tu = ph * 8 - 24;
        for (int i2 = tid; i2 < 2048; i2 += TPB) {
          int idx = 2 * i2;
          int rr = idx >> 9;
          int cc = idx & 511;
          float2 v = cld2(xh + (size_t)(Tu + rr) * 512 + cc);
          smVx[rr * 516 + cc] = v.x;
          smVx[rr * 516 + cc + 1] = v.y;
        }
        __syncthreads();
        const float4* v4 = (const float4*)(smVx + s * 516 + par * 256);
        float a = 0.f;
#pragma unroll
        for (int it = 0; it < 64; ++it) {
          float4 mm = m4[it], vv = v4[it];
          a += mm.x * vv.x + mm.y * vv.y + mm.z * vv.z + mm.w * vv.w;
        }
        a += __shfl_down(a, 1);
        if (par == 0) {
          float u = cld(&eh[(size_t)(Tu + s) * 128 + row]) - a;
          cst(&uh0[(size_t)(64 + Tu + s) * 128 + row], u);
        }
      }
      grid_barrier(arr, grp, bid, tid, (unsigned)(ph + 1));
    }
  }
}

// ---------------------------------------------------------------------------
// Epilogue: y_obs_t = C x_t; cost_t = y'Q y + u'R u.  (one WG per t)
// ---------------------------------------------------------------------------
__global__ __launch_bounds__(256) void cost_kernel(const float* __restrict__ C,
    const float* __restrict__ Q, const float* __restrict__ R,
    const float* __restrict__ xh, const float* __restrict__ uh0,
    float* __restrict__ out) {
  __shared__ float xs[512];
  __shared__ float ys[256];
  __shared__ float us[128];
  __shared__ float redw[4];
  const int t = blockIdx.x;
  const int tid = threadIdx.x;
  {
    float2 v = cld2(xh + (size_t)t * 512 + 2 * tid);
    xs[2 * tid] = v.x;
    xs[2 * tid + 1] = v.y;
  }
  if (tid < 64) {
    float2 v = cld2(uh0 + (size_t)(64 + t) * 128 + 2 * tid);
    us[2 * tid] = v.x;
    us[2 * tid + 1] = v.y;
  }
  __syncthreads();
  {
    const float4* m4 = (const float4*)(C + (size_t)tid * 512);
    const float4* v4 = (const float4*)xs;
    float a = 0.f;
    for (int it = 0; it < 128; ++it) {
      float4 mm = m4[it], vv = v4[it];
      a += mm.x * vv.x + mm.y * vv.y + mm.z * vv.z + mm.w * vv.w;
    }
    ys[tid] = a;
  }
  __syncthreads();
  float acc;
  {
    const float* Qr = Q + (size_t)tid * 256;
    float qy = 0.f;
    for (int k = 0; k < 256; ++k) qy = fmaf(Qr[k], ys[k], qy);
    acc = qy * ys[tid];
  }
  if (tid < 128) {
    const float* Rr = R + (size_t)tid * 128;
    float ru = 0.f;
    for (int k = 0; k < 128; ++k) ru = fmaf(Rr[k], us[k], ru);
    acc += ru * us[tid];
  }
  float v = acc;
  v += __shfl_xor(v, 32);
  v += __shfl_xor(v, 16);
  v += __shfl_xor(v, 8);
  v += __shfl_xor(v, 4);
  v += __shfl_xor(v, 2);
  v += __shfl_xor(v, 1);
  if ((tid & 63) == 0) redw[tid >> 6] = v;
  __syncthreads();
  if (tid == 0) out[t] = redw[0] + redw[1] + redw[2] + redw[3];
}

// ---------------------------------------------------------------------------
extern "C" void kernel_launch(void* const* d_in, const int* in_sizes, int n_in,
                              void* d_out, int out_size, void* d_ws, size_t ws_size,
                              hipStream_t stream) {
  (void)in_sizes; (void)n_in; (void)out_size; (void)ws_size;
  const float* A = (const float*)d_in[0];
  const float* B = (const float*)d_in[1];
  const float* C = (const float*)d_in[2];
  const float* Q = (const float*)d_in[3];
  const float* R = (const float*)d_in[4];
  const float* Km = (const float*)d_in[5];
  const float* MT = (const float*)d_in[6];
  const float* Phi = (const float*)d_in[7];
  const float* sm = (const float*)d_in[8];
  const float* x0 = (const float*)d_in[9];

  float* ws = (float*)d_ws;
  const int oWfir = 0;
  const int oKC = 2097152;
  const int oW0C = 2162688;
  const int oAcl = 2228224;
  const int oP = 2490368;            // 8 x 262144  (P[1..8])
  const int oCA = 4587520;           // 7 x 131072  (CA[1..7])
  const int oW0CA = 5505024;         // 7 x 65536   (W0CA[1..7])
  const int oRn = 5963776;           // 7 x 65536   (Rn[1..7])
  const int oApB = 6422528;          // 8 x 65536   (ApB[1..8])
  const int oAB33 = 6946816;         // 8 x 65536   (AB33[0..7])
  const int oCAB33 = 7471104;        // 7 x 32768
  const int oW0CAB33 = 7700480;      // 7 x 16384
  const int oA2 = 7815168;
  const int oA4 = 8077312;
  const int oA8 = 8339456;
  const int oA16 = 8601600;
  const int oA32 = 8863744;
  const int oM2 = 9125888;
  const int oBKC = oM2;
  const int oxh = 10174464;
  const int ouh0 = 10698752;
  const int oeh = 10838016;
  const int oynh = 10977280;
  const int odbnd = 11239424;
  const int oarr = 11306496;
  const int ogrp = oarr + NWG * 32;

  float* xh = ws + oxh;
  float* uh0 = ws + ouh0;
  float* eh = ws + oeh;
  float* ynh = ws + oynh;
  float* dbnd = ws + odbnd;
  unsigned* arr = (unsigned*)(ws + oarr);
  unsigned* grp = (unsigned*)(ws + ogrp);

  JobBatch jb;
  jb.n = 0;
  jb.start[0] = 0;
  auto J = [&](int xs_, int xo, int ys_, int yo, int zo, int M, int N, int K) {
    int i = jb.n++;
    jb.xsel[i] = xs_; jb.xoff[i] = xo; jb.ysel[i] = ys_; jb.yoff[i] = yo;
    jb.zoff[i] = zo; jb.M[i] = M; jb.N[i] = N; jb.K[i] = K;
    jb.start[i + 1] = jb.start[i] + (M >> 6) * (N >> 6);
  };
  auto L = [&]() {
    multi_gemm<<<dim3(jb.start[jb.n]), dim3(256), 0, stream>>>(jb, A, B, C, Km, ws);
    jb.n = 0;
    jb.start[0] = 0;
  };

  init_kernel<<<dim3(2048), dim3(256), 0, stream>>>(x0, xh, eh, ynh, uh0, dbnd,
                                                    arr, grp);
  m2_kernel<<<dim3(4096), dim3(256), 0, stream>>>(MT, sm, ws + oM2);
  wfir_kernel<<<dim3(8192), dim3(256), 0, stream>>>(ws + oM2, Phi, ws + oWfir);

  // ---- L1 ----
  J(4, 0, 3, 0, oKC, 128, 512, 256);
  J(1, 0, 1, 0, oA2, 512, 512, 512);
  J(1, 0, 2, 0, oApB, 512, 128, 512);
  J(3, 0, 1, 0, oCA, 256, 512, 512);
  L();
  // ---- L2 ----
  J(2, 0, 0, oKC, oBKC, 512, 512, 128);
  J(0, oA2, 0, oA2, oA4, 512, 512, 512);
  J(0, oCA, 1, 0, oCA + 131072, 256, 512, 512);
  J(1, 0, 0, oApB, oApB + 65536, 512, 128, 512);
  J(0, oWfir, 3, 0, oW0C, 128, 512, 256);
  L();
  axpy_acl<<<dim3(1024), dim3(256), 0, stream>>>(A, ws + oBKC, ws + oAcl, ws + oP);
  // ---- L3 ----
  J(0, oA4, 0, oA4, oA8, 512, 512, 512);
  J(0, oP, 0, oP, oP + 262144, 512, 512, 512);
  J(0, oCA, 0, oA2, oCA + 2 * 131072, 256, 512, 512);
  J(0, oCA + 131072, 0, oA2, oCA + 3 * 131072, 256, 512, 512);
  J(0, oW0C, 1, 0, oW0CA, 128, 512, 512);
  J(0, oW0C, 0, oA2, oW0CA + 65536, 128, 512, 512);
  J(0, oA2, 0, oApB, oApB + 2 * 65536, 512, 128, 512);
  J(0, oA2, 0, oApB + 65536, oApB + 3 * 65536, 512, 128, 512);
  L();
  // ---- L4 ----
  J(0, oA8, 0, oA8, oA16, 512, 512, 512);
  J(0, oP, 0, oP + 262144, oP + 2 * 262144, 512, 512, 512);
  J(0, oP + 262144, 0, oP + 262144, oP + 3 * 262144, 512, 512, 512);
  for (int i = 1; i <= 3; ++i)
    J(0, oCA + (i - 1) * 131072, 0, oA4, oCA + (i + 3) * 131072, 256, 512, 512);
  for (int i = 1; i <= 2; ++i)
    J(0, oW0CA + (i - 1) * 65536, 0, oA2, oW0CA + (i + 1) * 65536, 128, 512, 512);
  for (int k = 1; k <= 4; ++k)
    J(0, oA4, 0, oApB + (k - 1) * 65536, oApB + (k + 3) * 65536, 512, 128, 512);
  J(0, oP, 2, 0, oRn, 512, 128, 512);
  J(0, oP + 262144, 2, 0, oRn + 65536, 512, 128, 512);
  L();
  // ---- L5 ----
  J(0, oA16, 0, oA16, oA32, 512, 512, 512);
  for (int i = 1; i <= 4; ++i)
    J(0, oP + (i - 1) * 262144, 0, oP + 3 * 262144, oP + (i + 3) * 262144, 512, 512, 512);
  for (int i = 1; i <= 3; ++i)
    J(0, oW0CA + (i - 1) * 65536, 0, oA4, oW0CA + (i + 3) * 65536, 128, 512, 512);
  J(0, oP + 2 * 262144, 2, 0, oRn + 2 * 65536, 512, 128, 512);
  J(0, oP + 3 * 262144, 2, 0, oRn + 3 * 65536, 512, 128, 512);
  L();
  // ---- L6 ----
  for (int m = 0; m <= 7; ++m)
    J(0, oA32, 0, oApB + m * 65536, oAB33 + m * 65536, 512, 128, 512);
  for (int i = 5; i <= 7; ++i)
    J(0, oP + (i - 1) * 262144, 2, 0, oRn + (i - 1) * 65536, 512, 128, 512);
  L();
  // ---- L7 ----
  for (int m = 0; m <= 6; ++m)
    J(3, 0, 0, oAB33 + m * 65536, oCAB33 + m * 32768, 256, 128, 512);
  for (int m = 0; m <= 6; ++m)
    J(0, oW0C, 0, oAB33 + m * 65536, oW0CAB33 + m * 16384, 128, 128, 512);
  L();

  main_kernel<<<dim3(NWG), dim3(TPB), 0, stream>>>(
      B, C, x0, ws + oWfir, ws + oKC, ws + oW0C, ws + oP, ws + oCA,
      ws + oW0CA, ws + oRn, ws + oAB33, ws + oCAB33, ws + oW0CAB33,
      ws + oA8, xh, uh0, eh, ynh, dbnd, arr, grp);

  cost_kernel<<<dim3(1024), dim3(256), 0, stream>>>(C, Q, R, xh, uh0,
                                                    (float*)d_out);
}

// Round 11
// 3209.975 us; speedup vs baseline: 1.0460x; 1.0460x over previous
//
#include <hip/hip_runtime.h>

#define TPB 256
#define MAXJ 48

// role bases (flag index = blockIdx.x)
#define SC_N 128
#define YD0 128  // 32 WGs
#define YU0 160  // 7
#define WD0 167  // 8
#define WU0 175  // 7
#define DT0 182  // 16
#define XP0 198  // 32
#define XR0 230  // 16
#define U0 246   // 8
#define NWG 254

// ---------------------------------------------------------------------------
// Coherent (agent-scope, MALL-served) helpers: sc1 loads/stores, no fences.
// ---------------------------------------------------------------------------
__device__ __forceinline__ void cst(float* p, float v) {
  __hip_atomic_store(p, v, __ATOMIC_RELAXED, __HIP_MEMORY_SCOPE_AGENT);
}
__device__ __forceinline__ void cstu(unsigned* p, unsigned v) {
  __hip_atomic_store(p, v, __ATOMIC_RELAXED, __HIP_MEMORY_SCOPE_AGENT);
}
__device__ __forceinline__ unsigned cldu(const unsigned* p) {
  return __hip_atomic_load(p, __ATOMIC_RELAXED, __HIP_MEMORY_SCOPE_AGENT);
}
__device__ __forceinline__ float cld(const float* p) {
  return __hip_atomic_load(p, __ATOMIC_RELAXED, __HIP_MEMORY_SCOPE_AGENT);
}
__device__ __forceinline__ float2 cld2(const float* p) {
  unsigned long long u = __hip_atomic_load(
      reinterpret_cast<const unsigned long long*>(p), __ATOMIC_RELAXED,
      __HIP_MEMORY_SCOPE_AGENT);
  float2 v;
  __builtin_memcpy(&v, &u, 8);
  return v;
}

// ---------------------------------------------------------------------------
// Dataflow wait: lanes [laneBase, laneBase+n) poll producer WG flags
// [lo, lo+n) until >= v. v<=0 -> no wait. Distinct laneBase per range lets
// all of a consumer's waits resolve in ONE poll round.
// ---------------------------------------------------------------------------
__device__ __forceinline__ void waitr(unsigned* __restrict__ arr, int lo, int n,
                                      int v, int tid, int laneBase) {
  if (v <= 0) return;
  int idx = tid - laneBase;
  if (idx >= 0 && idx < n) {
    while (cldu(arr + ((lo + idx) << 5)) < (unsigned)v) __builtin_amdgcn_s_sleep(1);
  }
}

// Publish: drain this wave's stores/atomics to the coherence point, sync all
// waves, then one lane stores the monotonic flag (value = ph+1).
#define SETFLAG(ph)                                              \
  do {                                                           \
    asm volatile("s_waitcnt vmcnt(0)" ::: "memory");             \
    __syncthreads();                                             \
    if (tid == 0) cstu(arr + (bid << 5), (unsigned)((ph) + 1));  \
  } while (0)

#define WAITSYNC()                            \
  do {                                        \
    __atomic_signal_fence(__ATOMIC_SEQ_CST);  \
    __syncthreads();                          \
  } while (0)

// ---------------------------------------------------------------------------
// Tiled fp32 GEMM tile body.
// ---------------------------------------------------------------------------
__device__ void gemm_tile(const float* __restrict__ X, const float* __restrict__ Y,
                          float* __restrict__ Z, int M, int N, int Kd,
                          int mtile, int ntile) {
  __shared__ float Xs[16][65];
  __shared__ float Ys[16][65];
  const int tx = threadIdx.x & 15;
  const int ty = threadIdx.x >> 4;
  const int mbase = mtile * 64;
  const int nbase = ntile * 64;
  float acc[4][4] = {};
  for (int k0 = 0; k0 < Kd; k0 += 16) {
#pragma unroll
    for (int r = 0; r < 4; ++r) {
      int idx = threadIdx.x + 256 * r;
      int mm = idx >> 4, kk = idx & 15;
      int gm = mbase + mm, gk = k0 + kk;
      Xs[kk][mm] = (gm < M && gk < Kd) ? X[(size_t)gm * Kd + gk] : 0.f;
      int nn = idx & 63, k2 = idx >> 6;
      int gn = nbase + nn, gk2 = k0 + k2;
      Ys[k2][nn] = (gk2 < Kd && gn < N) ? Y[(size_t)gk2 * N + gn] : 0.f;
    }
    __syncthreads();
#pragma unroll
    for (int kk = 0; kk < 16; ++kk) {
      float xv[4], yv[4];
#pragma unroll
      for (int a = 0; a < 4; ++a) xv[a] = Xs[kk][ty * 4 + a];
#pragma unroll
      for (int b = 0; b < 4; ++b) yv[b] = Ys[kk][tx * 4 + b];
#pragma unroll
      for (int a = 0; a < 4; ++a)
#pragma unroll
        for (int b = 0; b < 4; ++b) acc[a][b] += xv[a] * yv[b];
    }
    __syncthreads();
  }
#pragma unroll
  for (int a = 0; a < 4; ++a) {
    int gm = mbase + ty * 4 + a;
    if (gm < M) {
#pragma unroll
      for (int b = 0; b < 4; ++b) {
        int gn = nbase + tx * 4 + b;
        if (gn < N) Z[(size_t)gm * N + gn] = acc[a][b];
      }
    }
  }
}

struct JobBatch {
  int n;
  int start[MAXJ + 1];
  int xsel[MAXJ], xoff[MAXJ], ysel[MAXJ], yoff[MAXJ], zoff[MAXJ];
  int M[MAXJ], N[MAXJ], K[MAXJ];
};

__global__ __launch_bounds__(256) void multi_gemm(JobBatch jb,
    const float* __restrict__ A, const float* __restrict__ Bm,
    const float* __restrict__ C, const float* __restrict__ Km,
    float* __restrict__ ws) {
  int b = blockIdx.x;
  int j = 0;
  while (j < jb.n - 1 && b >= jb.start[j + 1]) ++j;
  int rel = b - jb.start[j];
  const float* bases[5] = {ws, A, Bm, C, Km};
  const float* X = bases[jb.xsel[j]] + jb.xoff[j];
  const float* Y = bases[jb.ysel[j]] + jb.yoff[j];
  float* Z = ws + jb.zoff[j];
  int tn = jb.N[j] >> 6;
  gemm_tile(X, Y, Z, jb.M[j], jb.N[j], jb.K[j], rel / tn, rel % tn);
}

// ---------------------------------------------------------------------------
__global__ __launch_bounds__(256) void m2_kernel(const float* __restrict__ MT,
    const float* __restrict__ sm, float* __restrict__ M2g) {
  int idx = blockIdx.x * 256 + threadIdx.x;
  if (idx >= 128 * 32 * 256) return;
  int q = idx & 255;
  int ci = idx >> 8;
  const float* base = MT + (size_t)ci * 32 * 256 + q;
  float acc = 0.f;
#pragma unroll
  for (int j = 0; j < 32; ++j) acc += base[j * 256] * sm[j];
  M2g[idx] = acc;
}

__global__ __launch_bounds__(256) void wfir_kernel(const float* __restrict__ M2g,
    const float* __restrict__ Phi, float* __restrict__ W) {
  int idx = blockIdx.x * 256 + threadIdx.x;  // j*32768 + c*256 + q
  if (idx >= 64 * 32768) return;
  int j = idx >> 15;
  int cq = idx & 32767;
  int c = cq >> 8;
  int q = cq & 255;
  float acc = 0.f;
#pragma unroll
  for (int i = 0; i < 32; ++i)
    acc = fmaf(Phi[(i << 6) | j], M2g[(size_t)(((c << 5) | i) << 8) | q], acc);
  W[idx] = acc;
}

__global__ __launch_bounds__(256) void axpy_acl(const float* __restrict__ A,
    const float* __restrict__ BKC, float* __restrict__ Acl, float* __restrict__ P1) {
  int i = blockIdx.x * 256 + threadIdx.x;
  if (i < 262144) {
    float v = A[i] - BKC[i];
    Acl[i] = v;
    P1[i] = v;
  }
}

// ---------------------------------------------------------------------------
__global__ void init_kernel(const float* __restrict__ x0, float* __restrict__ xh,
    float* __restrict__ eh, float* __restrict__ ynh, float* __restrict__ uh0,
    float* __restrict__ dbnd, unsigned* __restrict__ arr) {
  int i = blockIdx.x * 256 + threadIdx.x;
  int stride = gridDim.x * 256;
  for (int k = i; k < 524288; k += stride) cst(xh + k, 0.f);
  for (int k = i; k < 139264; k += stride) cst(eh + k, 0.f);
  for (int k = i; k < 262144; k += stride) cst(ynh + k, 0.f);
  for (int k = i; k < 8192; k += stride) cst(uh0 + k, 0.f);
  for (int k = i; k < NWG * 32; k += stride) cstu(arr + k, 0u);
  if (i < 512) cst(dbnd + i, x0[i]);
}

// ---------------------------------------------------------------------------
// Persistent dataflow loop: NO global barrier. Each role loops over its own
// phase window, waiting only on its producers' flag ranges (RAW edges):
//   SC(ph)  <- Yd(ph-1), Yu(ph-1)
//   Yd,Wd(ph) <- Dt(ph-1)
//   Yu,Wu(ph) <- U(ph-1)        [ph>=4]
//   Dt(ph)  <- Dt(ph-1), U(ph-1) [ph>=4]
//   Xp(ph)  <- Xp(ph-1), Xr(ph-1) [ph>=3]
//   Xr(ph)  <- SC(ph-1), Wd(ph-2), Wu(ph-2)
//   U(ph)   <- Xp(ph-1), Xr(ph-1), SC(ph-2), Wd(ph-3), Wu(ph-3)
// All buffers are append-only along t -> no WAR hazards; flags monotonic.
// Throughput = max dependency-cycle mean (Dt self-loop; 5-phase U->...->U).
// ---------------------------------------------------------------------------
__global__ __launch_bounds__(TPB, 1) void main_kernel(
    const float* __restrict__ B, const float* __restrict__ C,
    const float* __restrict__ x0, const float* __restrict__ Wfir,
    const float* __restrict__ KC, const float* __restrict__ W0C,
    const float* __restrict__ Pp, const float* __restrict__ CAp,
    const float* __restrict__ W0CAp, const float* __restrict__ Rnp,
    const float* __restrict__ AB33p, const float* __restrict__ CAB33p,
    const float* __restrict__ W0CAB33p, const float* __restrict__ A8k,
    float* __restrict__ xh, float* __restrict__ uh0, float* __restrict__ eh,
    float* __restrict__ ynh, float* __restrict__ dbnd,
    unsigned* __restrict__ arr) {
  __shared__ float smA[64 * 256];
  __shared__ float smY[8 * 256];
  __shared__ float smV[512];
  __shared__ float smW[8 * 128];
  __shared__ float smVx[8 * 516];
  __shared__ float redsc[4][16];
  const int bid = blockIdx.x;
  const int tid = threadIdx.x;

  if (bid < SC_N) {
    // ================= SC =================  (ph 1..128)
    for (int i = tid; i < 16384; i += TPB) {
      int j = i >> 8;
      smA[i] = (j >= 1) ? Wfir[(size_t)j * 32768 + bid * 256 + (i & 255)] : 0.f;
    }
    __syncthreads();
#pragma unroll 1
    for (int ph = 1; ph <= 128; ++ph) {
      waitr(arr, YD0, 32, ph, tid, 0);
      waitr(arr, YU0, 7, ph, tid, 32);
      WAITSYNC();
      const int Ty = ph * 8 - 8;
      for (int i2 = tid; i2 < 1024; i2 += TPB) {
        float2 v = cld2(ynh + (size_t)Ty * 256 + 2 * i2);
        smY[2 * i2] = v.x;
        smY[2 * i2 + 1] = v.y;
      }
      __syncthreads();
      const int q = tid;
      float yreg[8];
#pragma unroll
      for (int s = 0; s < 8; ++s) yreg[s] = smY[s * 256 + q];
      const int wv = tid >> 6;
      const int lane = tid & 63;
#pragma unroll
      for (int kt = 0; kt < 5; ++kt) {
        const int r0 = 1 + 16 * kt;
        float wreg[23];
#pragma unroll
        for (int i = 0; i < 23; ++i) {
          const int j = r0 - 7 + i;
          wreg[i] = (j >= 1 && j <= 63) ? smA[j * 256 + q] : 0.f;
        }
        float acc[16];
#pragma unroll
        for (int a = 0; a < 16; ++a) acc[a] = 0.f;
#pragma unroll
        for (int a = 0; a < 16; ++a)
#pragma unroll
          for (int s = 0; s < 8; ++s) acc[a] += wreg[a + 7 - s] * yreg[s];
#pragma unroll
        for (int a = 0; a < 16; ++a) {
          float v = acc[a];
          v += __shfl_xor(v, 32);
          v += __shfl_xor(v, 16);
          v += __shfl_xor(v, 8);
          v += __shfl_xor(v, 4);
          v += __shfl_xor(v, 2);
          v += __shfl_xor(v, 1);
          if (lane == 0) redsc[wv][a] = v;
        }
        __syncthreads();
        if (tid < 16) {
          const int r = r0 + tid;
          if (r <= 70) {
            float sum = redsc[0][tid] + redsc[1][tid] + redsc[2][tid] + redsc[3][tid];
            atomicAdd(&eh[(size_t)(Ty + r) * 128 + bid], sum);
          }
        }
        __syncthreads();
      }
      SETFLAG(ph);
    }
  } else if (bid < YU0) {
    // ================= Yd =================  (ph 0..127)
    const int r = bid - YD0;
    const int s = r >> 2;
    const int qtr = (r & 3) * 64;
    const int row = qtr + (tid >> 2);
    const int ks = (tid & 3) * 128;
    const float* Mrow = (s == 0) ? C : (CAp + (size_t)(s - 1) * 131072);
    const float4* m4 = (const float4*)(Mrow + (size_t)row * 512 + ks);
#pragma unroll 1
    for (int ph = 0; ph < 128; ++ph) {
      waitr(arr, DT0, 16, ph, tid, 0);
      WAITSYNC();
      const int T = ph * 8;
      {
        float2 v = cld2(dbnd + (size_t)ph * 512 + 2 * tid);
        smV[2 * tid] = v.x;
        smV[2 * tid + 1] = v.y;
      }
      __syncthreads();
      const float4* v4 = (const float4*)(smV + ks);
      float a = 0.f;
#pragma unroll
      for (int it = 0; it < 32; ++it) {
        float4 mm = m4[it], vv = v4[it];
        a += mm.x * vv.x + mm.y * vv.y + mm.z * vv.z + mm.w * vv.w;
      }
      a += __shfl_down(a, 2);
      a += __shfl_down(a, 1);
      if ((tid & 3) == 0) atomicAdd(&ynh[(size_t)(T + s) * 256 + row], a);
      SETFLAG(ph);
    }
  } else if (bid < WD0) {
    // ================= Yu =================  (ph 0..127)
    const int m = bid - YU0;
    const int row = tid;
    const float4* m4 = (const float4*)(CAB33p + (size_t)m * 32768 + (size_t)row * 128);
#pragma unroll 1
    for (int ph = 0; ph < 128; ++ph) {
      waitr(arr, U0, 8, (ph >= 4 ? ph : 0), tid, 0);
      WAITSYNC();
      const int T = ph * 8;
      for (int i2 = tid; i2 < 512; i2 += TPB) {
        float2 v = cld2(uh0 + (size_t)(64 + T - 33) * 128 + 2 * i2);
        smW[2 * i2] = v.x;
        smW[2 * i2 + 1] = v.y;
      }
      __syncthreads();
      float acc[8];
#pragma unroll
      for (int s = 0; s < 8; ++s) acc[s] = 0.f;
#pragma unroll 4
      for (int it = 0; it < 32; ++it) {
        float4 mm = m4[it];
#pragma unroll
        for (int s = 0; s < 8; ++s) {
          if (s > m) {
            float4 vv = ((const float4*)(smW + (s - m - 1) * 128))[it];
            acc[s] += mm.x * vv.x + mm.y * vv.y + mm.z * vv.z + mm.w * vv.w;
          }
        }
      }
#pragma unroll
      for (int s = 0; s < 8; ++s)
        if (s > m) atomicAdd(&ynh[(size_t)(T + s) * 256 + row], acc[s]);
      SETFLAG(ph);
    }
  } else if (bid < WU0) {
    // ================= Wd =================  (ph 0..127)
    const int s = bid - WD0;
    const int row = tid >> 1;
    const int seg = tid & 1;
    const float* Mrow = (s == 0) ? W0C : (W0CAp + (size_t)(s - 1) * 65536);
    const float4* m4 = (const float4*)(Mrow + (size_t)row * 512 + seg * 256);
#pragma unroll 1
    for (int ph = 0; ph < 128; ++ph) {
      waitr(arr, DT0, 16, ph, tid, 0);
      WAITSYNC();
      const int T = ph * 8;
      {
        float2 v = cld2(dbnd + (size_t)ph * 512 + 2 * tid);
        smV[2 * tid] = v.x;
        smV[2 * tid + 1] = v.y;
      }
      __syncthreads();
      const float4* v4 = (const float4*)(smV + seg * 256);
      float a = 0.f;
#pragma unroll
      for (int it = 0; it < 64; ++it) {
        float4 mm = m4[it], vv = v4[it];
        a += mm.x * vv.x + mm.y * vv.y + mm.z * vv.z + mm.w * vv.w;
      }
      a += __shfl_down(a, 1);
      if (seg == 0) atomicAdd(&eh[(size_t)(T + s) * 128 + row], a);
      SETFLAG(ph);
    }
  } else if (bid < DT0) {
    // ================= Wu =================  (ph 0..127)
    const int m = bid - WU0;
    const int row = tid >> 1;
    const int seg = tid & 1;
    const float4* m4 = (const float4*)(W0CAB33p + (size_t)m * 16384 + (size_t)row * 128 + seg * 64);
#pragma unroll 1
    for (int ph = 0; ph < 128; ++ph) {
      waitr(arr, U0, 8, (ph >= 4 ? ph : 0), tid, 0);
      WAITSYNC();
      const int T = ph * 8;
      for (int i2 = tid; i2 < 512; i2 += TPB) {
        float2 v = cld2(uh0 + (size_t)(64 + T - 33) * 128 + 2 * i2);
        smW[2 * i2] = v.x;
        smW[2 * i2 + 1] = v.y;
      }
      __syncthreads();
      float acc[8];
#pragma unroll
      for (int s = 0; s < 8; ++s) acc[s] = 0.f;
#pragma unroll 4
      for (int it = 0; it < 16; ++it) {
        float4 mm = m4[it];
#pragma unroll
        for (int s = 0; s < 8; ++s) {
          if (s > m) {
            float4 vv = ((const float4*)(smW + (s - m - 1) * 128 + seg * 64))[it];
            acc[s] += mm.x * vv.x + mm.y * vv.y + mm.z * vv.z + mm.w * vv.w;
          }
        }
      }
#pragma unroll
      for (int s = 0; s < 8; ++s) {
        if (s > m) {
          float v = acc[s];
          v += __shfl_down(v, 1);
          if (seg == 0) atomicAdd(&eh[(size_t)(T + s) * 128 + row], v);
        }
      }
      SETFLAG(ph);
    }
  } else if (bid < XP0) {
    // ================= Dt =================  (ph 0..126)
    const int g = bid - DT0;
    const int row = g * 32 + (tid >> 3);
    const int l8 = tid & 7;
#pragma unroll 1
    for (int ph = 0; ph <= 126; ++ph) {
      waitr(arr, DT0, 16, ph, tid, 0);
      waitr(arr, U0, 8, (ph >= 4 ? ph : 0), tid, 16);
      WAITSYNC();
      const int T = ph * 8;
      {
        float2 v = cld2(dbnd + (size_t)ph * 512 + 2 * tid);
        smV[2 * tid] = v.x;
        smV[2 * tid + 1] = v.y;
      }
      for (int i2 = tid; i2 < 512; i2 += TPB) {
        float2 v = cld2(uh0 + (size_t)(64 + T - 33) * 128 + 2 * i2);
        smW[2 * i2] = v.x;
        smW[2 * i2 + 1] = v.y;
      }
      __syncthreads();
      float a = 0.f;
      {
        const float4* m4 = (const float4*)(A8k + (size_t)row * 512 + l8 * 64);
        const float4* v4 = (const float4*)(smV + l8 * 64);
#pragma unroll
        for (int it = 0; it < 16; ++it) {
          float4 mm = m4[it], vv = v4[it];
          a += mm.x * vv.x + mm.y * vv.y + mm.z * vv.z + mm.w * vv.w;
        }
      }
#pragma unroll
      for (int m = 0; m < 8; ++m) {
        const float4* m4 = (const float4*)(AB33p + (size_t)m * 65536 + (size_t)row * 128 + l8 * 16);
        const float4* v4 = (const float4*)(smW + (7 - m) * 128 + l8 * 16);
#pragma unroll
        for (int it = 0; it < 4; ++it) {
          float4 mm = m4[it], vv = v4[it];
          a += mm.x * vv.x + mm.y * vv.y + mm.z * vv.z + mm.w * vv.w;
        }
      }
      a += __shfl_down(a, 4);
      a += __shfl_down(a, 2);
      a += __shfl_down(a, 1);
      if (l8 == 0) cst(&dbnd[(size_t)(ph + 1) * 512 + row], a);
      SETFLAG(ph);
    }
  } else if (bid < XR0) {
    // ================= Xp =================  (ph 2..129)
    const int r = bid - XP0;
    const int s = r >> 2;
    const int qtr = (r & 3) << 7;
    const int row = qtr + (tid >> 1);
    const int seg = tid & 1;
#pragma unroll 1
    for (int ph = 2; ph <= 129; ++ph) {
      waitr(arr, XP0, 32, (ph >= 3 ? ph : 0), tid, 0);
      waitr(arr, XR0, 16, (ph >= 3 ? ph : 0), tid, 32);
      WAITSYNC();
      const int Tq = ph * 8 - 16;
      {
        const float* src = (ph == 2) ? x0 : (xh + (size_t)(Tq - 1) * 512);
        float2 v = cld2(src + 2 * tid);
        smV[2 * tid] = v.x;
        smV[2 * tid + 1] = v.y;
      }
      __syncthreads();
      const int pslot = (ph == 2) ? s : (s + 1);
      if (pslot == 0) {
        if (seg == 0) atomicAdd(&xh[(size_t)Tq * 512 + row], smV[row]);
      } else {
        const float4* m4 = (const float4*)(Pp + (size_t)(pslot - 1) * 262144 +
                                           (size_t)row * 512 + seg * 256);
        const float4* v4 = (const float4*)(smV + seg * 256);
        float a = 0.f;
#pragma unroll
        for (int it = 0; it < 64; ++it) {
          float4 mm = m4[it], vv = v4[it];
          a += mm.x * vv.x + mm.y * vv.y + mm.z * vv.z + mm.w * vv.w;
        }
        a += __shfl_down(a, 1);
        if (seg == 0) atomicAdd(&xh[(size_t)(Tq + s) * 512 + row], a);
      }
      SETFLAG(ph);
    }
  } else if (bid < U0) {
    // ================= Xr =================  (ph 2..129)
    const int r = bid - XR0;
    const int i = r >> 1;
    const int half = (r & 1) << 8;
    const int row = half + tid;
    const float* Rrow = (i == 0) ? (B + (size_t)row * 128)
                                 : (Rnp + (size_t)(i - 1) * 65536 + (size_t)row * 128);
    const float4* m4 = (const float4*)Rrow;
#pragma unroll 1
    for (int ph = 2; ph <= 129; ++ph) {
      waitr(arr, 0, SC_N, ph, tid, 0);
      waitr(arr, WD0, 8, ph - 1, tid, 128);
      waitr(arr, WU0, 7, ph - 1, tid, 136);
      WAITSYNC();
      const int Tq = ph * 8 - 16;
      for (int i2 = tid; i2 < 512; i2 += TPB) {
        int idx = 2 * i2;
        float2 v;
        if (ph == 2 && idx < 128) {
          v.x = 0.f;
          v.y = 0.f;
        } else {
          v = cld2(eh + (size_t)(Tq - 1) * 128 + idx);
        }
        smW[idx] = v.x;
        smW[idx + 1] = v.y;
      }
      __syncthreads();
      float acc[8];
#pragma unroll
      for (int s = 0; s < 8; ++s) acc[s] = 0.f;
#pragma unroll 4
      for (int it = 0; it < 32; ++it) {
        float4 mm = m4[it];
#pragma unroll
        for (int s = 0; s < 8; ++s) {
          if (s >= i) {
            float4 vv = ((const float4*)(smW + (s - i) * 128))[it];
            acc[s] += mm.x * vv.x + mm.y * vv.y + mm.z * vv.z + mm.w * vv.w;
          }
        }
      }
#pragma unroll
      for (int s = 0; s < 8; ++s)
        if (s >= i) atomicAdd(&xh[(size_t)(Tq + s) * 512 + row], acc[s]);
      SETFLAG(ph);
    }
  } else {
    // ================= U =================  (ph 3..130)
    const int g = bid - U0;
    const int o = tid >> 1;
    const int par = tid & 1;
    const int s = o >> 4;
    const int lr = o & 15;
    const int row = g * 16 + lr;
    const float4* m4 = (const float4*)(KC + (size_t)row * 512 + par * 256);
#pragma unroll 1
    for (int ph = 3; ph <= 130; ++ph) {
      waitr(arr, XP0, 32, ph, tid, 0);
      waitr(arr, XR0, 16, ph, tid, 32);
      waitr(arr, 0, SC_N, ph - 1, tid, 48);
      waitr(arr, WD0, 8, ph - 2, tid, 176);
      waitr(arr, WU0, 7, ph - 2, tid, 184);
      WAITSYNC();
      const int Tu = ph * 8 - 24;
      for (int i2 = tid; i2 < 2048; i2 += TPB) {
        int idx = 2 * i2;
        int rr = idx >> 9;
        int cc = idx & 511;
        float2 v = cld2(xh + (size_t)(Tu + rr) * 512 + cc);
        smVx[rr * 516 + cc] = v.x;
        smVx[rr * 516 + cc + 1] = v.y;
      }
      __syncthreads();
      const float4* v4 = (const float4*)(smVx + s * 516 + par * 256);
      float a = 0.f;
#pragma unroll
      for (int it = 0; it < 64; ++it) {
        float4 mm = m4[it], vv = v4[it];
        a += mm.x * vv.x + mm.y * vv.y + mm.z * vv.z + mm.w * vv.w;
      }
      a += __shfl_down(a, 1);
      if (par == 0) {
        float u = cld(&eh[(size_t)(Tu + s) * 128 + row]) - a;
        cst(&uh0[(size_t)(64 + Tu + s) * 128 + row], u);
      }
      SETFLAG(ph);
    }
  }
}

// ---------------------------------------------------------------------------
// Epilogue: y_obs_t = C x_t; cost_t = y'Q y + u'R u.  (one WG per t)
// ---------------------------------------------------------------------------
__global__ __launch_bounds__(256) void cost_kernel(const float* __restrict__ C,
    const float* __restrict__ Q, const float* __restrict__ R,
    const float* __restrict__ xh, const float* __restrict__ uh0,
    float* __restrict__ out) {
  __shared__ float xs[512];
  __shared__ float ys[256];
  __shared__ float us[128];
  __shared__ float redw[4];
  const int t = blockIdx.x;
  const int tid = threadIdx.x;
  {
    float2 v = cld2(xh + (size_t)t * 512 + 2 * tid);
    xs[2 * tid] = v.x;
    xs[2 * tid + 1] = v.y;
  }
  if (tid < 64) {
    float2 v = cld2(uh0 + (size_t)(64 + t) * 128 + 2 * tid);
    us[2 * tid] = v.x;
    us[2 * tid + 1] = v.y;
  }
  __syncthreads();
  {
    const float4* m4 = (const float4*)(C + (size_t)tid * 512);
    const float4* v4 = (const float4*)xs;
    float a = 0.f;
    for (int it = 0; it < 128; ++it) {
      float4 mm = m4[it], vv = v4[it];
      a += mm.x * vv.x + mm.y * vv.y + mm.z * vv.z + mm.w * vv.w;
    }
    ys[tid] = a;
  }
  __syncthreads();
  float acc;
  {
    const float* Qr = Q + (size_t)tid * 256;
    float qy = 0.f;
    for (int k = 0; k < 256; ++k) qy = fmaf(Qr[k], ys[k], qy);
    acc = qy * ys[tid];
  }
  if (tid < 128) {
    const float* Rr = R + (size_t)tid * 128;
    float ru = 0.f;
    for (int k = 0; k < 128; ++k) ru = fmaf(Rr[k], us[k], ru);
    acc += ru * us[tid];
  }
  float v = acc;
  v += __shfl_xor(v, 32);
  v += __shfl_xor(v, 16);
  v += __shfl_xor(v, 8);
  v += __shfl_xor(v, 4);
  v += __shfl_xor(v, 2);
  v += __shfl_xor(v, 1);
  if ((tid & 63) == 0) redw[tid >> 6] = v;
  __syncthreads();
  if (tid == 0) out[t] = redw[0] + redw[1] + redw[2] + redw[3];
}

// ---------------------------------------------------------------------------
extern "C" void kernel_launch(void* const* d_in, const int* in_sizes, int n_in,
                              void* d_out, int out_size, void* d_ws, size_t ws_size,
                              hipStream_t stream) {
  (void)in_sizes; (void)n_in; (void)out_size; (void)ws_size;
  const float* A = (const float*)d_in[0];
  const float* B = (const float*)d_in[1];
  const float* C = (const float*)d_in[2];
  const float* Q = (const float*)d_in[3];
  const float* R = (const float*)d_in[4];
  const float* Km = (const float*)d_in[5];
  const float* MT = (const float*)d_in[6];
  const float* Phi = (const float*)d_in[7];
  const float* sm = (const float*)d_in[8];
  const float* x0 = (const float*)d_in[9];

  float* ws = (float*)d_ws;
  const int oWfir = 0;
  const int oKC = 2097152;
  const int oW0C = 2162688;
  const int oAcl = 2228224;
  const int oP = 2490368;            // 8 x 262144  (P[1..8])
  const int oCA = 4587520;           // 7 x 131072  (CA[1..7])
  const int oW0CA = 5505024;         // 7 x 65536   (W0CA[1..7])
  const int oRn = 5963776;           // 7 x 65536   (Rn[1..7])
  const int oApB = 6422528;          // 8 x 65536   (ApB[1..8])
  const int oAB33 = 6946816;         // 8 x 65536   (AB33[0..7])
  const int oCAB33 = 7471104;        // 7 x 32768
  const int oW0CAB33 = 7700480;      // 7 x 16384
  const int oA2 = 7815168;
  const int oA4 = 8077312;
  const int oA8 = 8339456;
  const int oA16 = 8601600;
  const int oA32 = 8863744;
  const int oM2 = 9125888;
  const int oBKC = oM2;
  const int oxh = 10174464;
  const int ouh0 = 10698752;
  const int oeh = 10838016;
  const int oynh = 10977280;
  const int odbnd = 11239424;
  const int oarr = 11306496;

  float* xh = ws + oxh;
  float* uh0 = ws + ouh0;
  float* eh = ws + oeh;
  float* ynh = ws + oynh;
  float* dbnd = ws + odbnd;
  unsigned* arr = (unsigned*)(ws + oarr);

  JobBatch jb;
  jb.n = 0;
  jb.start[0] = 0;
  auto J = [&](int xs_, int xo, int ys_, int yo, int zo, int M, int N, int K) {
    int i = jb.n++;
    jb.xsel[i] = xs_; jb.xoff[i] = xo; jb.ysel[i] = ys_; jb.yoff[i] = yo;
    jb.zoff[i] = zo; jb.M[i] = M; jb.N[i] = N; jb.K[i] = K;
    jb.start[i + 1] = jb.start[i] + (M >> 6) * (N >> 6);
  };
  auto L = [&]() {
    multi_gemm<<<dim3(jb.start[jb.n]), dim3(256), 0, stream>>>(jb, A, B, C, Km, ws);
    jb.n = 0;
    jb.start[0] = 0;
  };

  init_kernel<<<dim3(2048), dim3(256), 0, stream>>>(x0, xh, eh, ynh, uh0, dbnd,
                                                    arr);
  m2_kernel<<<dim3(4096), dim3(256), 0, stream>>>(MT, sm, ws + oM2);
  wfir_kernel<<<dim3(8192), dim3(256), 0, stream>>>(ws + oM2, Phi, ws + oWfir);

  // ---- L1 ----
  J(4, 0, 3, 0, oKC, 128, 512, 256);
  J(1, 0, 1, 0, oA2, 512, 512, 512);
  J(1, 0, 2, 0, oApB, 512, 128, 512);
  J(3, 0, 1, 0, oCA, 256, 512, 512);
  L();
  // ---- L2 ----
  J(2, 0, 0, oKC, oBKC, 512, 512, 128);
  J(0, oA2, 0, oA2, oA4, 512, 512, 512);
  J(0, oCA, 1, 0, oCA + 131072, 256, 512, 512);
  J(1, 0, 0, oApB, oApB + 65536, 512, 128, 512);
  J(0, oWfir, 3, 0, oW0C, 128, 512, 256);
  L();
  axpy_acl<<<dim3(1024), dim3(256), 0, stream>>>(A, ws + oBKC, ws + oAcl, ws + oP);
  // ---- L3 ----
  J(0, oA4, 0, oA4, oA8, 512, 512, 512);
  J(0, oP, 0, oP, oP + 262144, 512, 512, 512);
  J(0, oCA, 0, oA2, oCA + 2 * 131072, 256, 512, 512);
  J(0, oCA + 131072, 0, oA2, oCA + 3 * 131072, 256, 512, 512);
  J(0, oW0C, 1, 0, oW0CA, 128, 512, 512);
  J(0, oW0C, 0, oA2, oW0CA + 65536, 128, 512, 512);
  J(0, oA2, 0, oApB, oApB + 2 * 65536, 512, 128, 512);
  J(0, oA2, 0, oApB + 65536, oApB + 3 * 65536, 512, 128, 512);
  L();
  // ---- L4 ----
  J(0, oA8, 0, oA8, oA16, 512, 512, 512);
  J(0, oP, 0, oP + 262144, oP + 2 * 262144, 512, 512, 512);
  J(0, oP + 262144, 0, oP + 262144, oP + 3 * 262144, 512, 512, 512);
  for (int i = 1; i <= 3; ++i)
    J(0, oCA + (i - 1) * 131072, 0, oA4, oCA + (i + 3) * 131072, 256, 512, 512);
  for (int i = 1; i <= 2; ++i)
    J(0, oW0CA + (i - 1) * 65536, 0, oA2, oW0CA + (i + 1) * 65536, 128, 512, 512);
  for (int k = 1; k <= 4; ++k)
    J(0, oA4, 0, oApB + (k - 1) * 65536, oApB + (k + 3) * 65536, 512, 128, 512);
  J(0, oP, 2, 0, oRn, 512, 128, 512);
  J(0, oP + 262144, 2, 0, oRn + 65536, 512, 128, 512);
  L();
  // ---- L5 ----
  J(0, oA16, 0, oA16, oA32, 512, 512, 512);
  for (int i = 1; i <= 4; ++i)
    J(0, oP + (i - 1) * 262144, 0, oP + 3 * 262144, oP + (i + 3) * 262144, 512, 512, 512);
  for (int i = 1; i <= 3; ++i)
    J(0, oW0CA + (i - 1) * 65536, 0, oA4, oW0CA + (i + 3) * 65536, 128, 512, 512);
  J(0, oP + 2 * 262144, 2, 0, oRn + 2 * 65536, 512, 128, 512);
  J(0, oP + 3 * 262144, 2, 0, oRn + 3 * 65536, 512, 128, 512);
  L();
  // ---- L6 ----
  for (int m = 0; m <= 7; ++m)
    J(0, oA32, 0, oApB + m * 65536, oAB33 + m * 65536, 512, 128, 512);
  for (int i = 5; i <= 7; ++i)
    J(0, oP + (i - 1) * 262144, 2, 0, oRn + (i - 1) * 65536, 512, 128, 512);
  L();
  // ---- L7 ----
  for (int m = 0; m <= 6; ++m)
    J(3, 0, 0, oAB33 + m * 65536, oCAB33 + m * 32768, 256, 128, 512);
  for (int m = 0; m <= 6; ++m)
    J(0, oW0C, 0, oAB33 + m * 65536, oW0CAB33 + m * 16384, 128, 128, 512);
  L();

  main_kernel<<<dim3(NWG), dim3(TPB), 0, stream>>>(
      B, C, x0, ws + oWfir, ws + oKC, ws + oW0C, ws + oP, ws + oCA,
      ws + oW0CA, ws + oRn, ws + oAB33, ws + oCAB33, ws + oW0CAB33,
      ws + oA8, xh, uh0, eh, ynh, dbnd, arr);

  cost_kernel<<<dim3(1024), dim3(256), 0, stream>>>(C, Q, R, xh, uh0,
                                                    (float*)d_out);
}

// Round 12
// 3130.521 us; speedup vs baseline: 1.0725x; 1.0254x over previous
//
#include <hip/hip_runtime.h>

#define TPB 256
#define MAXJ 48

// role bases (flag index = blockIdx.x)
#define SC_N 128
#define YD0 128  // 32 WGs
#define YU0 160  // 7
#define WD0 167  // 8
#define WU0 175  // 7
#define DT0 182  // 16  (also barrier checkers; DT0 is root)
#define XP0 198  // 32
#define XR0 230  // 16
#define U0 246   // 8
#define NWG 254

// ---------------------------------------------------------------------------
// Coherent (agent-scope, MALL-served) helpers: sc1 loads/stores, no fences.
// ---------------------------------------------------------------------------
__device__ __forceinline__ void cst(float* p, float v) {
  __hip_atomic_store(p, v, __ATOMIC_RELAXED, __HIP_MEMORY_SCOPE_AGENT);
}
__device__ __forceinline__ void cstu(unsigned* p, unsigned v) {
  __hip_atomic_store(p, v, __ATOMIC_RELAXED, __HIP_MEMORY_SCOPE_AGENT);
}
__device__ __forceinline__ unsigned cldu(const unsigned* p) {
  return __hip_atomic_load(p, __ATOMIC_RELAXED, __HIP_MEMORY_SCOPE_AGENT);
}
__device__ __forceinline__ float cld(const float* p) {
  return __hip_atomic_load(p, __ATOMIC_RELAXED, __HIP_MEMORY_SCOPE_AGENT);
}
__device__ __forceinline__ float2 cld2(const float* p) {
  unsigned long long u = __hip_atomic_load(
      reinterpret_cast<const unsigned long long*>(p), __ATOMIC_RELAXED,
      __HIP_MEMORY_SCOPE_AGENT);
  float2 v;
  __builtin_memcpy(&v, &u, 8);
  return v;
}

// ---------------------------------------------------------------------------
// Fan-in-capped tree barrier. Max same-line poll fan-in = 16 (vs 254 flat):
//   1) every WG stores its arrival flag (line polled by exactly 1 checker lane)
//   2) checkers (Dt WGs, one per 16-WG group) poll their group's 16 arrival
//      lines on 16 lanes, then store a group line (polled by 1 root lane)
//   3) root (bid==DT0) polls 16 group lines, then stores 16 BROADCAST copies
//   4) each WG polls the broadcast copy of its own group (fan-in <= 16)
// vmcnt(0) drains this WG's sc1 stores/atomics to the coherence point first.
// ---------------------------------------------------------------------------
__device__ __forceinline__ void tree_barrier(unsigned* __restrict__ arr,
                                             unsigned* __restrict__ gl,
                                             unsigned* __restrict__ bc,
                                             int bid, int tid, unsigned v) {
  asm volatile("s_waitcnt vmcnt(0)" ::: "memory");
  __syncthreads();
  if (tid == 0) cstu(arr + (bid << 5), v);
  if (bid >= DT0 && bid < DT0 + 16) {
    const int g = bid - DT0;
    const int lo = g << 4;
    const int n = (NWG - lo < 16) ? (NWG - lo) : 16;
    if (tid < n) {
      while (cldu(arr + ((lo + tid) << 5)) < v) __builtin_amdgcn_s_sleep(2);
    }
    __syncthreads();
    if (tid == 0) cstu(gl + (g << 5), v);
  }
  if (bid == DT0) {
    if (tid < 16) {
      while (cldu(gl + (tid << 5)) < v) __builtin_amdgcn_s_sleep(2);
    }
    __syncthreads();
    if (tid < 16) cstu(bc + (tid << 5), v);
  }
  if (tid == 0) {
    const int g = bid >> 4;
    while (cldu(bc + (g << 5)) < v) __builtin_amdgcn_s_sleep(2);
  }
  __atomic_signal_fence(__ATOMIC_SEQ_CST);
  __syncthreads();
}

// ---------------------------------------------------------------------------
// Tiled fp32 GEMM tile body.
// ---------------------------------------------------------------------------
__device__ void gemm_tile(const float* __restrict__ X, const float* __restrict__ Y,
                          float* __restrict__ Z, int M, int N, int Kd,
                          int mtile, int ntile) {
  __shared__ float Xs[16][65];
  __shared__ float Ys[16][65];
  const int tx = threadIdx.x & 15;
  const int ty = threadIdx.x >> 4;
  const int mbase = mtile * 64;
  const int nbase = ntile * 64;
  float acc[4][4] = {};
  for (int k0 = 0; k0 < Kd; k0 += 16) {
#pragma unroll
    for (int r = 0; r < 4; ++r) {
      int idx = threadIdx.x + 256 * r;
      int mm = idx >> 4, kk = idx & 15;
      int gm = mbase + mm, gk = k0 + kk;
      Xs[kk][mm] = (gm < M && gk < Kd) ? X[(size_t)gm * Kd + gk] : 0.f;
      int nn = idx & 63, k2 = idx >> 6;
      int gn = nbase + nn, gk2 = k0 + k2;
      Ys[k2][nn] = (gk2 < Kd && gn < N) ? Y[(size_t)gk2 * N + gn] : 0.f;
    }
    __syncthreads();
#pragma unroll
    for (int kk = 0; kk < 16; ++kk) {
      float xv[4], yv[4];
#pragma unroll
      for (int a = 0; a < 4; ++a) xv[a] = Xs[kk][ty * 4 + a];
#pragma unroll
      for (int b = 0; b < 4; ++b) yv[b] = Ys[kk][tx * 4 + b];
#pragma unroll
      for (int a = 0; a < 4; ++a)
#pragma unroll
        for (int b = 0; b < 4; ++b) acc[a][b] += xv[a] * yv[b];
    }
    __syncthreads();
  }
#pragma unroll
  for (int a = 0; a < 4; ++a) {
    int gm = mbase + ty * 4 + a;
    if (gm < M) {
#pragma unroll
      for (int b = 0; b < 4; ++b) {
        int gn = nbase + tx * 4 + b;
        if (gn < N) Z[(size_t)gm * N + gn] = acc[a][b];
      }
    }
  }
}

struct JobBatch {
  int n;
  int start[MAXJ + 1];
  int xsel[MAXJ], xoff[MAXJ], ysel[MAXJ], yoff[MAXJ], zoff[MAXJ];
  int M[MAXJ], N[MAXJ], K[MAXJ];
};

__global__ __launch_bounds__(256) void multi_gemm(JobBatch jb,
    const float* __restrict__ A, const float* __restrict__ Bm,
    const float* __restrict__ C, const float* __restrict__ Km,
    float* __restrict__ ws) {
  int b = blockIdx.x;
  int j = 0;
  while (j < jb.n - 1 && b >= jb.start[j + 1]) ++j;
  int rel = b - jb.start[j];
  const float* bases[5] = {ws, A, Bm, C, Km};
  const float* X = bases[jb.xsel[j]] + jb.xoff[j];
  const float* Y = bases[jb.ysel[j]] + jb.yoff[j];
  float* Z = ws + jb.zoff[j];
  int tn = jb.N[j] >> 6;
  gemm_tile(X, Y, Z, jb.M[j], jb.N[j], jb.K[j], rel / tn, rel % tn);
}

// ---------------------------------------------------------------------------
__global__ __launch_bounds__(256) void m2_kernel(const float* __restrict__ MT,
    const float* __restrict__ sm, float* __restrict__ M2g) {
  int idx = blockIdx.x * 256 + threadIdx.x;
  if (idx >= 128 * 32 * 256) return;
  int q = idx & 255;
  int ci = idx >> 8;
  const float* base = MT + (size_t)ci * 32 * 256 + q;
  float acc = 0.f;
#pragma unroll
  for (int j = 0; j < 32; ++j) acc += base[j * 256] * sm[j];
  M2g[idx] = acc;
}

__global__ __launch_bounds__(256) void wfir_kernel(const float* __restrict__ M2g,
    const float* __restrict__ Phi, float* __restrict__ W) {
  int idx = blockIdx.x * 256 + threadIdx.x;  // j*32768 + c*256 + q
  if (idx >= 64 * 32768) return;
  int j = idx >> 15;
  int cq = idx & 32767;
  int c = cq >> 8;
  int q = cq & 255;
  float acc = 0.f;
#pragma unroll
  for (int i = 0; i < 32; ++i)
    acc = fmaf(Phi[(i << 6) | j], M2g[(size_t)(((c << 5) | i) << 8) | q], acc);
  W[idx] = acc;
}

__global__ __launch_bounds__(256) void axpy_acl(const float* __restrict__ A,
    const float* __restrict__ BKC, float* __restrict__ Acl, float* __restrict__ P1) {
  int i = blockIdx.x * 256 + threadIdx.x;
  if (i < 262144) {
    float v = A[i] - BKC[i];
    Acl[i] = v;
    P1[i] = v;
  }
}

// ---------------------------------------------------------------------------
__global__ void init_kernel(const float* __restrict__ x0, float* __restrict__ xh,
    float* __restrict__ eh, float* __restrict__ ynh, float* __restrict__ uh0,
    float* __restrict__ dbnd, unsigned* __restrict__ arr,
    unsigned* __restrict__ gl, unsigned* __restrict__ bc) {
  int i = blockIdx.x * 256 + threadIdx.x;
  int stride = gridDim.x * 256;
  for (int k = i; k < 524288; k += stride) cst(xh + k, 0.f);
  for (int k = i; k < 139264; k += stride) cst(eh + k, 0.f);
  for (int k = i; k < 262144; k += stride) cst(ynh + k, 0.f);
  for (int k = i; k < 8192; k += stride) cst(uh0 + k, 0.f);
  for (int k = i; k < NWG * 32; k += stride) cstu(arr + k, 0u);
  for (int k = i; k < 16 * 32; k += stride) {
    cstu(gl + k, 0u);
    cstu(bc + k, 0u);
  }
  if (i < 512) cst(dbnd + i, x0[i]);
}

// ---------------------------------------------------------------------------
// Persistent main loop: 131 phases x ONE tree barrier. T=8*ph. Lag schedule:
//   SC (0..127)  : e_fir block ph-1 GATHER: e_fir[t][c]=sum_j W[j][c].y[t-j]
//                  (per-thread 72-deep register ring of y column; no atomics)
//   Yd (128..159): y[T+s] += CA[s] d_T
//   Yu (160..166): y[T+s] += sum_m CAB33[m] u[..]  (loop-swapped)
//   Wd (167..174): eh[T+s] += W0CA[s] d_T
//   Wu (175..181): eh[T+s] += sum_m W0CAB33[m] u[..]
//   Dt (182..197): dbnd[ph+1] = A8 d_T + sum AB33[m] u[..]  (+barrier duty)
//   Xp (198..229): x[Tq+s] += P[s+1] x[Tq-1], Tq=T-16
//   Xr (230..245): x[Tq+s] += sum_i Rn[i] (eh+e_fir)[Tq+s-1-i]
//   U  (246..253): u[Tu+s] = (eh+e_fir)[Tu+s] - KC x[Tu+s], Tu=T-24
// ---------------------------------------------------------------------------
__global__ __launch_bounds__(TPB, 1) void main_kernel(
    const float* __restrict__ B, const float* __restrict__ C,
    const float* __restrict__ x0, const float* __restrict__ Wfir,
    const float* __restrict__ KC, const float* __restrict__ W0C,
    const float* __restrict__ Pp, const float* __restrict__ CAp,
    const float* __restrict__ W0CAp, const float* __restrict__ Rnp,
    const float* __restrict__ AB33p, const float* __restrict__ CAB33p,
    const float* __restrict__ W0CAB33p, const float* __restrict__ A8k,
    float* __restrict__ xh, float* __restrict__ uh0, float* __restrict__ eh,
    float* __restrict__ efir, float* __restrict__ ynh, float* __restrict__ dbnd,
    unsigned* __restrict__ arr, unsigned* __restrict__ gl,
    unsigned* __restrict__ bc) {
  __shared__ float smA[64 * 256];
  __shared__ float smV[512];
  __shared__ float smW[8 * 128];
  __shared__ float smVx[8 * 516];
  __shared__ float redsc[4][16];
  const int bid = blockIdx.x;
  const int tid = threadIdx.x;

  if (bid < SC_N) {
    // ================= SC (gather form) =================
    for (int i = tid; i < 16384; i += TPB) {
      int j = i >> 8;
      smA[i] = (j >= 1) ? Wfir[(size_t)j * 32768 + bid * 256 + (i & 255)] : 0.f;
    }
    __syncthreads();
    float ring[72];
#pragma unroll
    for (int k = 0; k < 72; ++k) ring[k] = 0.f;
    const int wv = tid >> 6;
    const int lane = tid & 63;
#pragma unroll 1
    for (int ph = 0; ph <= 130; ++ph) {
      if (ph >= 1 && ph < 129) {
        const int Ty = ph * 8 - 8;
        // shift ring by one block, append y block ph-1 (this thread's column)
#pragma unroll
        for (int k = 0; k < 64; ++k) ring[k] = ring[k + 8];
#pragma unroll
        for (int s = 0; s < 8; ++s)
          ring[64 + s] = cld(ynh + (size_t)(Ty + s) * 256 + tid);
        float acc[8];
#pragma unroll
        for (int s = 0; s < 8; ++s) acc[s] = 0.f;
#pragma unroll
        for (int m = 1; m <= 63; ++m) {
          float w = smA[m * 256 + tid];
#pragma unroll
          for (int s = 0; s < 8; ++s) acc[s] = fmaf(w, ring[64 + s - m], acc[s]);
        }
#pragma unroll
        for (int s = 0; s < 8; ++s) {
          float v = acc[s];
          v += __shfl_xor(v, 32);
          v += __shfl_xor(v, 16);
          v += __shfl_xor(v, 8);
          v += __shfl_xor(v, 4);
          v += __shfl_xor(v, 2);
          v += __shfl_xor(v, 1);
          if (lane == 0) redsc[wv][s] = v;
        }
        __syncthreads();
        if (tid < 8) {
          float sum = redsc[0][tid] + redsc[1][tid] + redsc[2][tid] + redsc[3][tid];
          cst(efir + (size_t)(Ty + tid) * 128 + bid, sum);
        }
      }
      tree_barrier(arr, gl, bc, bid, tid, (unsigned)(ph + 1));
    }
  } else if (bid < YU0) {
    // ================= Yd =================
    const int r = bid - YD0;
    const int s = r >> 2;
    const int qtr = (r & 3) * 64;
    const int row = qtr + (tid >> 2);
    const int ks = (tid & 3) * 128;
    const float* Mrow = (s == 0) ? C : (CAp + (size_t)(s - 1) * 131072);
    const float4* m4 = (const float4*)(Mrow + (size_t)row * 512 + ks);
#pragma unroll 1
    for (int ph = 0; ph <= 130; ++ph) {
      if (ph < 128) {
        const int T = ph * 8;
        {
          float2 v = cld2(dbnd + (size_t)ph * 512 + 2 * tid);
          smV[2 * tid] = v.x;
          smV[2 * tid + 1] = v.y;
        }
        __syncthreads();
        const float4* v4 = (const float4*)(smV + ks);
        float a = 0.f;
#pragma unroll
        for (int it = 0; it < 32; ++it) {
          float4 mm = m4[it], vv = v4[it];
          a += mm.x * vv.x + mm.y * vv.y + mm.z * vv.z + mm.w * vv.w;
        }
        a += __shfl_down(a, 2);
        a += __shfl_down(a, 1);
        if ((tid & 3) == 0) atomicAdd(&ynh[(size_t)(T + s) * 256 + row], a);
      }
      tree_barrier(arr, gl, bc, bid, tid, (unsigned)(ph + 1));
    }
  } else if (bid < WD0) {
    // ================= Yu =================
    const int m = bid - YU0;
    const int row = tid;
    const float4* m4 = (const float4*)(CAB33p + (size_t)m * 32768 + (size_t)row * 128);
#pragma unroll 1
    for (int ph = 0; ph <= 130; ++ph) {
      if (ph < 128) {
        const int T = ph * 8;
        for (int i2 = tid; i2 < 512; i2 += TPB) {
          float2 v = cld2(uh0 + (size_t)(64 + T - 33) * 128 + 2 * i2);
          smW[2 * i2] = v.x;
          smW[2 * i2 + 1] = v.y;
        }
        __syncthreads();
        float acc[8];
#pragma unroll
        for (int s = 0; s < 8; ++s) acc[s] = 0.f;
#pragma unroll 4
        for (int it = 0; it < 32; ++it) {
          float4 mm = m4[it];
#pragma unroll
          for (int s = 0; s < 8; ++s) {
            if (s > m) {
              float4 vv = ((const float4*)(smW + (s - m - 1) * 128))[it];
              acc[s] += mm.x * vv.x + mm.y * vv.y + mm.z * vv.z + mm.w * vv.w;
            }
          }
        }
#pragma unroll
        for (int s = 0; s < 8; ++s)
          if (s > m) atomicAdd(&ynh[(size_t)(T + s) * 256 + row], acc[s]);
      }
      tree_barrier(arr, gl, bc, bid, tid, (unsigned)(ph + 1));
    }
  } else if (bid < WU0) {
    // ================= Wd =================
    const int s = bid - WD0;
    const int row = tid >> 1;
    const int seg = tid & 1;
    const float* Mrow = (s == 0) ? W0C : (W0CAp + (size_t)(s - 1) * 65536);
    const float4* m4 = (const float4*)(Mrow + (size_t)row * 512 + seg * 256);
#pragma unroll 1
    for (int ph = 0; ph <= 130; ++ph) {
      if (ph < 128) {
        const int T = ph * 8;
        {
          float2 v = cld2(dbnd + (size_t)ph * 512 + 2 * tid);
          smV[2 * tid] = v.x;
          smV[2 * tid + 1] = v.y;
        }
        __syncthreads();
        const float4* v4 = (const float4*)(smV + seg * 256);
        float a = 0.f;
#pragma unroll
        for (int it = 0; it < 64; ++it) {
          float4 mm = m4[it], vv = v4[it];
          a += mm.x * vv.x + mm.y * vv.y + mm.z * vv.z + mm.w * vv.w;
        }
        a += __shfl_down(a, 1);
        if (seg == 0) atomicAdd(&eh[(size_t)(T + s) * 128 + row], a);
      }
      tree_barrier(arr, gl, bc, bid, tid, (unsigned)(ph + 1));
    }
  } else if (bid < DT0) {
    // ================= Wu =================
    const int m = bid - WU0;
    const int row = tid >> 1;
    const int seg = tid & 1;
    const float4* m4 = (const float4*)(W0CAB33p + (size_t)m * 16384 + (size_t)row * 128 + seg * 64);
#pragma unroll 1
    for (int ph = 0; ph <= 130; ++ph) {
      if (ph < 128) {
        const int T = ph * 8;
        for (int i2 = tid; i2 < 512; i2 += TPB) {
          float2 v = cld2(uh0 + (size_t)(64 + T - 33) * 128 + 2 * i2);
          smW[2 * i2] = v.x;
          smW[2 * i2 + 1] = v.y;
        }
        __syncthreads();
        float acc[8];
#pragma unroll
        for (int s = 0; s < 8; ++s) acc[s] = 0.f;
#pragma unroll 4
        for (int it = 0; it < 16; ++it) {
          float4 mm = m4[it];
#pragma unroll
          for (int s = 0; s < 8; ++s) {
            if (s > m) {
              float4 vv = ((const float4*)(smW + (s - m - 1) * 128 + seg * 64))[it];
              acc[s] += mm.x * vv.x + mm.y * vv.y + mm.z * vv.z + mm.w * vv.w;
            }
          }
        }
#pragma unroll
        for (int s = 0; s < 8; ++s) {
          if (s > m) {
            float v = acc[s];
            v += __shfl_down(v, 1);
            if (seg == 0) atomicAdd(&eh[(size_t)(T + s) * 128 + row], v);
          }
        }
      }
      tree_barrier(arr, gl, bc, bid, tid, (unsigned)(ph + 1));
    }
  } else if (bid < XP0) {
    // ================= Dt ================= (+ barrier checker duty)
    const int g = bid - DT0;
    const int row = g * 32 + (tid >> 3);
    const int l8 = tid & 7;
#pragma unroll 1
    for (int ph = 0; ph <= 130; ++ph) {
      if (ph < 127) {
        const int T = ph * 8;
        {
          float2 v = cld2(dbnd + (size_t)ph * 512 + 2 * tid);
          smV[2 * tid] = v.x;
          smV[2 * tid + 1] = v.y;
        }
        for (int i2 = tid; i2 < 512; i2 += TPB) {
          float2 v = cld2(uh0 + (size_t)(64 + T - 33) * 128 + 2 * i2);
          smW[2 * i2] = v.x;
          smW[2 * i2 + 1] = v.y;
        }
        __syncthreads();
        float a = 0.f;
        {
          const float4* m4 = (const float4*)(A8k + (size_t)row * 512 + l8 * 64);
          const float4* v4 = (const float4*)(smV + l8 * 64);
#pragma unroll
          for (int it = 0; it < 16; ++it) {
            float4 mm = m4[it], vv = v4[it];
            a += mm.x * vv.x + mm.y * vv.y + mm.z * vv.z + mm.w * vv.w;
          }
        }
#pragma unroll
        for (int m = 0; m < 8; ++m) {
          const float4* m4 = (const float4*)(AB33p + (size_t)m * 65536 + (size_t)row * 128 + l8 * 16);
          const float4* v4 = (const float4*)(smW + (7 - m) * 128 + l8 * 16);
#pragma unroll
          for (int it = 0; it < 4; ++it) {
            float4 mm = m4[it], vv = v4[it];
            a += mm.x * vv.x + mm.y * vv.y + mm.z * vv.z + mm.w * vv.w;
          }
        }
        a += __shfl_down(a, 4);
        a += __shfl_down(a, 2);
        a += __shfl_down(a, 1);
        if (l8 == 0) cst(&dbnd[(size_t)(ph + 1) * 512 + row], a);
      }
      tree_barrier(arr, gl, bc, bid, tid, (unsigned)(ph + 1));
    }
  } else if (bid < XR0) {
    // ================= Xp =================
    const int r = bid - XP0;
    const int s = r >> 2;
    const int qtr = (r & 3) << 7;
    const int row = qtr + (tid >> 1);
    const int seg = tid & 1;
#pragma unroll 1
    for (int ph = 0; ph <= 130; ++ph) {
      if (ph >= 2 && ph < 130) {
        const int Tq = ph * 8 - 16;
        {
          const float* src = (ph == 2) ? x0 : (xh + (size_t)(Tq - 1) * 512);
          float2 v = cld2(src + 2 * tid);
          smV[2 * tid] = v.x;
          smV[2 * tid + 1] = v.y;
        }
        __syncthreads();
        const int pslot = (ph == 2) ? s : (s + 1);
        if (pslot == 0) {
          if (seg == 0) atomicAdd(&xh[(size_t)Tq * 512 + row], smV[row]);
        } else {
          const float4* m4 = (const float4*)(Pp + (size_t)(pslot - 1) * 262144 +
                                             (size_t)row * 512 + seg * 256);
          const float4* v4 = (const float4*)(smV + seg * 256);
          float a = 0.f;
#pragma unroll
          for (int it = 0; it < 64; ++it) {
            float4 mm = m4[it], vv = v4[it];
            a += mm.x * vv.x + mm.y * vv.y + mm.z * vv.z + mm.w * vv.w;
          }
          a += __shfl_down(a, 1);
          if (seg == 0) atomicAdd(&xh[(size_t)(Tq + s) * 512 + row], a);
        }
      }
      tree_barrier(arr, gl, bc, bid, tid, (unsigned)(ph + 1));
    }
  } else if (bid < U0) {
    // ================= Xr =================
    const int r = bid - XR0;
    const int i = r >> 1;
    const int half = (r & 1) << 8;
    const int row = half + tid;
    const float* Rrow = (i == 0) ? (B + (size_t)row * 128)
                                 : (Rnp + (size_t)(i - 1) * 65536 + (size_t)row * 128);
    const float4* m4 = (const float4*)Rrow;
#pragma unroll 1
    for (int ph = 0; ph <= 130; ++ph) {
      if (ph >= 2 && ph < 130) {
        const int Tq = ph * 8 - 16;
        for (int i2 = tid; i2 < 512; i2 += TPB) {
          int idx = 2 * i2;
          float2 v;
          if (ph == 2 && idx < 128) {
            v.x = 0.f;
            v.y = 0.f;
          } else {
            float2 a2 = cld2(eh + (size_t)(Tq - 1) * 128 + idx);
            float2 b2 = cld2(efir + (size_t)(Tq - 1) * 128 + idx);
            v.x = a2.x + b2.x;
            v.y = a2.y + b2.y;
          }
          smW[idx] = v.x;
          smW[idx + 1] = v.y;
        }
        __syncthreads();
        float acc[8];
#pragma unroll
        for (int s = 0; s < 8; ++s) acc[s] = 0.f;
#pragma unroll 4
        for (int it = 0; it < 32; ++it) {
          float4 mm = m4[it];
#pragma unroll
          for (int s = 0; s < 8; ++s) {
            if (s >= i) {
              float4 vv = ((const float4*)(smW + (s - i) * 128))[it];
              acc[s] += mm.x * vv.x + mm.y * vv.y + mm.z * vv.z + mm.w * vv.w;
            }
          }
        }
#pragma unroll
        for (int s = 0; s < 8; ++s)
          if (s >= i) atomicAdd(&xh[(size_t)(Tq + s) * 512 + row], acc[s]);
      }
      tree_barrier(arr, gl, bc, bid, tid, (unsigned)(ph + 1));
    }
  } else {
    // ================= U =================
    const int g = bid - U0;
    const int o = tid >> 1;
    const int par = tid & 1;
    const int s = o >> 4;
    const int lr = o & 15;
    const int row = g * 16 + lr;
    const float4* m4 = (const float4*)(KC + (size_t)row * 512 + par * 256);
#pragma unroll 1
    for (int ph = 0; ph <= 130; ++ph) {
      if (ph >= 3) {
        const int Tu = ph * 8 - 24;
        for (int i2 = tid; i2 < 2048; i2 += TPB) {
          int idx = 2 * i2;
          int rr = idx >> 9;
          int cc = idx & 511;
          float2 v = cld2(xh + (size_t)(Tu + rr) * 512 + cc);
          smVx[rr * 516 + cc] = v.x;
          smVx[rr * 516 + cc + 1] = v.y;
        }
        __syncthreads();
        const float4* v4 = (const float4*)(smVx + s * 516 + par * 256);
        float a = 0.f;
#pragma unroll
        for (int it = 0; it < 64; ++it) {
          float4 mm = m4[it], vv = v4[it];
          a += mm.x * vv.x + mm.y * vv.y + mm.z * vv.z + mm.w * vv.w;
        }
        a += __shfl_down(a, 1);
        if (par == 0) {
          float u = cld(&eh[(size_t)(Tu + s) * 128 + row]) +
                    cld(&efir[(size_t)(Tu + s) * 128 + row]) - a;
          cst(&uh0[(size_t)(64 + Tu + s) * 128 + row], u);
        }
      }
      tree_barrier(arr, gl, bc, bid, tid, (unsigned)(ph + 1));
    }
  }
}

// ---------------------------------------------------------------------------
// Epilogue: y_obs_t = C x_t; cost_t = y'Q y + u'R u.  (one WG per t)
// ---------------------------------------------------------------------------
__global__ __launch_bounds__(256) void cost_kernel(const float* __restrict__ C,
    const float* __restrict__ Q, const float* __restrict__ R,
    const float* __restrict__ xh, const float* __restrict__ uh0,
    float* __restrict__ out) {
  __shared__ float xs[512];
  __shared__ float ys[256];
  __shared__ float us[128];
  __shared__ float redw[4];
  const int t = blockIdx.x;
  const int tid = threadIdx.x;
  {
    float2 v = cld2(xh + (size_t)t * 512 + 2 * tid);
    xs[2 * tid] = v.x;
    xs[2 * tid + 1] = v.y;
  }
  if (tid < 64) {
    float2 v = cld2(uh0 + (size_t)(64 + t) * 128 + 2 * tid);
    us[2 * tid] = v.x;
    us[2 * tid + 1] = v.y;
  }
  __syncthreads();
  {
    const float4* m4 = (const float4*)(C + (size_t)tid * 512);
    const float4* v4 = (const float4*)xs;
    float a = 0.f;
    for (int it = 0; it < 128; ++it) {
      float4 mm = m4[it], vv = v4[it];
      a += mm.x * vv.x + mm.y * vv.y + mm.z * vv.z + mm.w * vv.w;
    }
    ys[tid] = a;
  }
  __syncthreads();
  float acc;
  {
    const float* Qr = Q + (size_t)tid * 256;
    float qy = 0.f;
    for (int k = 0; k < 256; ++k) qy = fmaf(Qr[k], ys[k], qy);
    acc = qy * ys[tid];
  }
  if (tid < 128) {
    const float* Rr = R + (size_t)tid * 128;
    float ru = 0.f;
    for (int k = 0; k < 128; ++k) ru = fmaf(Rr[k], us[k], ru);
    acc += ru * us[tid];
  }
  float v = acc;
  v += __shfl_xor(v, 32);
  v += __shfl_xor(v, 16);
  v += __shfl_xor(v, 8);
  v += __shfl_xor(v, 4);
  v += __shfl_xor(v, 2);
  v += __shfl_xor(v, 1);
  if ((tid & 63) == 0) redw[tid >> 6] = v;
  __syncthreads();
  if (tid == 0) out[t] = redw[0] + redw[1] + redw[2] + redw[3];
}

// ---------------------------------------------------------------------------
extern "C" void kernel_launch(void* const* d_in, const int* in_sizes, int n_in,
                              void* d_out, int out_size, void* d_ws, size_t ws_size,
                              hipStream_t stream) {
  (void)in_sizes; (void)n_in; (void)out_size; (void)ws_size;
  const float* A = (const float*)d_in[0];
  const float* B = (const float*)d_in[1];
  const float* C = (const float*)d_in[2];
  const float* Q = (const float*)d_in[3];
  const float* R = (const float*)d_in[4];
  const float* Km = (const float*)d_in[5];
  const float* MT = (const float*)d_in[6];
  const float* Phi = (const float*)d_in[7];
  const float* sm = (const float*)d_in[8];
  const float* x0 = (const float*)d_in[9];

  float* ws = (float*)d_ws;
  const int oWfir = 0;
  const int oKC = 2097152;
  const int oW0C = 2162688;
  const int oAcl = 2228224;
  const int oP = 2490368;            // 8 x 262144  (P[1..8])
  const int oCA = 4587520;           // 7 x 131072  (CA[1..7])
  const int oW0CA = 5505024;         // 7 x 65536   (W0CA[1..7])
  const int oRn = 5963776;           // 7 x 65536   (Rn[1..7])
  const int oApB = 6422528;          // 8 x 65536   (ApB[1..8])
  const int oAB33 = 6946816;         // 8 x 65536   (AB33[0..7])
  const int oCAB33 = 7471104;        // 7 x 32768
  const int oW0CAB33 = 7700480;      // 7 x 16384
  const int oA2 = 7815168;
  const int oA4 = 8077312;
  const int oA8 = 8339456;
  const int oA16 = 8601600;
  const int oA32 = 8863744;
  const int oM2 = 9125888;
  const int oBKC = oM2;
  const int oxh = 10174464;
  const int ouh0 = 10698752;
  const int oeh = 10838016;
  const int oynh = 10977280;
  const int odbnd = 11239424;
  const int oefir = 11306496;        // 1024x128 = 131072
  const int oarr = 11437568;         // NWG*32
  const int ogl = oarr + NWG * 32;   // 16*32
  const int obc = ogl + 512;         // 16*32

  float* xh = ws + oxh;
  float* uh0 = ws + ouh0;
  float* eh = ws + oeh;
  float* ynh = ws + oynh;
  float* dbnd = ws + odbnd;
  float* efir = ws + oefir;
  unsigned* arr = (unsigned*)(ws + oarr);
  unsigned* gl = (unsigned*)(ws + ogl);
  unsigned* bc = (unsigned*)(ws + obc);

  JobBatch jb;
  jb.n = 0;
  jb.start[0] = 0;
  auto J = [&](int xs_, int xo, int ys_, int yo, int zo, int M, int N, int K) {
    int i = jb.n++;
    jb.xsel[i] = xs_; jb.xoff[i] = xo; jb.ysel[i] = ys_; jb.yoff[i] = yo;
    jb.zoff[i] = zo; jb.M[i] = M; jb.N[i] = N; jb.K[i] = K;
    jb.start[i + 1] = jb.start[i] + (M >> 6) * (N >> 6);
  };
  auto L = [&]() {
    multi_gemm<<<dim3(jb.start[jb.n]), dim3(256), 0, stream>>>(jb, A, B, C, Km, ws);
    jb.n = 0;
    jb.start[0] = 0;
  };

  init_kernel<<<dim3(2048), dim3(256), 0, stream>>>(x0, xh, eh, ynh, uh0, dbnd,
                                                    arr, gl, bc);
  m2_kernel<<<dim3(4096), dim3(256), 0, stream>>>(MT, sm, ws + oM2);
  wfir_kernel<<<dim3(8192), dim3(256), 0, stream>>>(ws + oM2, Phi, ws + oWfir);

  // ---- L1 ----
  J(4, 0, 3, 0, oKC, 128, 512, 256);
  J(1, 0, 1, 0, oA2, 512, 512, 512);
  J(1, 0, 2, 0, oApB, 512, 128, 512);
  J(3, 0, 1, 0, oCA, 256, 512, 512);
  L();
  // ---- L2 ----
  J(2, 0, 0, oKC, oBKC, 512, 512, 128);
  J(0, oA2, 0, oA2, oA4, 512, 512, 512);
  J(0, oCA, 1, 0, oCA + 131072, 256, 512, 512);
  J(1, 0, 0, oApB, oApB + 65536, 512, 128, 512);
  J(0, oWfir, 3, 0, oW0C, 128, 512, 256);
  L();
  axpy_acl<<<dim3(1024), dim3(256), 0, stream>>>(A, ws + oBKC, ws + oAcl, ws + oP);
  // ---- L3 ----
  J(0, oA4, 0, oA4, oA8, 512, 512, 512);
  J(0, oP, 0, oP, oP + 262144, 512, 512, 512);
  J(0, oCA, 0, oA2, oCA + 2 * 131072, 256, 512, 512);
  J(0, oCA + 131072, 0, oA2, oCA + 3 * 131072, 256, 512, 512);
  J(0, oW0C, 1, 0, oW0CA, 128, 512, 512);
  J(0, oW0C, 0, oA2, oW0CA + 65536, 128, 512, 512);
  J(0, oA2, 0, oApB, oApB + 2 * 65536, 512, 128, 512);
  J(0, oA2, 0, oApB + 65536, oApB + 3 * 65536, 512, 128, 512);
  L();
  // ---- L4 ----
  J(0, oA8, 0, oA8, oA16, 512, 512, 512);
  J(0, oP, 0, oP + 262144, oP + 2 * 262144, 512, 512, 512);
  J(0, oP + 262144, 0, oP + 262144, oP + 3 * 262144, 512, 512, 512);
  for (int i = 1; i <= 3; ++i)
    J(0, oCA + (i - 1) * 131072, 0, oA4, oCA + (i + 3) * 131072, 256, 512, 512);
  for (int i = 1; i <= 2; ++i)
    J(0, oW0CA + (i - 1) * 65536, 0, oA2, oW0CA + (i + 1) * 65536, 128, 512, 512);
  for (int k = 1; k <= 4; ++k)
    J(0, oA4, 0, oApB + (k - 1) * 65536, oApB + (k + 3) * 65536, 512, 128, 512);
  J(0, oP, 2, 0, oRn, 512, 128, 512);
  J(0, oP + 262144, 2, 0, oRn + 65536, 512, 128, 512);
  L();
  // ---- L5 ----
  J(0, oA16, 0, oA16, oA32, 512, 512, 512);
  for (int i = 1; i <= 4; ++i)
    J(0, oP + (i - 1) * 262144, 0, oP + 3 * 262144, oP + (i + 3) * 262144, 512, 512, 512);
  for (int i = 1; i <= 3; ++i)
    J(0, oW0CA + (i - 1) * 65536, 0, oA4, oW0CA + (i + 3) * 65536, 128, 512, 512);
  J(0, oP + 2 * 262144, 2, 0, oRn + 2 * 65536, 512, 128, 512);
  J(0, oP + 3 * 262144, 2, 0, oRn + 3 * 65536, 512, 128, 512);
  L();
  // ---- L6 ----
  for (int m = 0; m <= 7; ++m)
    J(0, oA32, 0, oApB + m * 65536, oAB33 + m * 65536, 512, 128, 512);
  for (int i = 5; i <= 7; ++i)
    J(0, oP + (i - 1) * 262144, 2, 0, oRn + (i - 1) * 65536, 512, 128, 512);
  L();
  // ---- L7 ----
  for (int m = 0; m <= 6; ++m)
    J(3, 0, 0, oAB33 + m * 65536, oCAB33 + m * 32768, 256, 128, 512);
  for (int m = 0; m <= 6; ++m)
    J(0, oW0C, 0, oAB33 + m * 65536, oW0CAB33 + m * 16384, 128, 128, 512);
  L();

  main_kernel<<<dim3(NWG), dim3(TPB), 0, stream>>>(
      B, C, x0, ws + oWfir, ws + oKC, ws + oW0C, ws + oP, ws + oCA,
      ws + oW0CA, ws + oRn, ws + oAB33, ws + oCAB33, ws + oW0CAB33,
      ws + oA8, xh, uh0, eh, efir, ynh, dbnd, arr, gl, bc);

  cost_kernel<<<dim3(1024), dim3(256), 0, stream>>>(C, Q, R, xh, uh0,
                                                    (float*)d_out);
}

// Round 13
// 3108.994 us; speedup vs baseline: 1.0800x; 1.0069x over previous
//
#include <hip/hip_runtime.h>

#define TPB 256
#define MAXJ 48

// role bases (flag index = blockIdx.x)
#define SC_N 128
#define YD0 128  // 32 WGs
#define YU0 160  // 7
#define WD0 167  // 8
#define WU0 175  // 7
#define DT0 182  // 16  (also barrier checkers; DT0 is root)
#define XP0 198  // 32
#define XR0 230  // 16
#define U0 246   // 8
#define NWG 254

// ---------------------------------------------------------------------------
// sc1 (coherence-point) helpers: ONLY for flag polls and data WRITES.
// Data READS use plain cached loads: every dynamic buffer is monotonic-append
// (a line is never read before its final write, never re-read by the same
// cache), so a cached read always misses to the MALL and gets fresh data,
// while the per-XCD L2 absorbs the broadcast fan-in that serialized sc1 reads.
// ---------------------------------------------------------------------------
__device__ __forceinline__ void cst(float* p, float v) {
  __hip_atomic_store(p, v, __ATOMIC_RELAXED, __HIP_MEMORY_SCOPE_AGENT);
}
__device__ __forceinline__ void cstu(unsigned* p, unsigned v) {
  __hip_atomic_store(p, v, __ATOMIC_RELAXED, __HIP_MEMORY_SCOPE_AGENT);
}
__device__ __forceinline__ unsigned cldu(const unsigned* p) {
  return __hip_atomic_load(p, __ATOMIC_RELAXED, __HIP_MEMORY_SCOPE_AGENT);
}
__device__ __forceinline__ float2 ld2(const float* p) {
  return *reinterpret_cast<const float2*>(p);
}

// ---------------------------------------------------------------------------
// Fan-in-capped tree barrier (R12). Flags remain sc1 (re-read lines).
// ---------------------------------------------------------------------------
__device__ __forceinline__ void tree_barrier(unsigned* __restrict__ arr,
                                             unsigned* __restrict__ gl,
                                             unsigned* __restrict__ bc,
                                             int bid, int tid, unsigned v) {
  asm volatile("s_waitcnt vmcnt(0)" ::: "memory");
  __syncthreads();
  if (tid == 0) cstu(arr + (bid << 5), v);
  if (bid >= DT0 && bid < DT0 + 16) {
    const int g = bid - DT0;
    const int lo = g << 4;
    const int n = (NWG - lo < 16) ? (NWG - lo) : 16;
    if (tid < n) {
      while (cldu(arr + ((lo + tid) << 5)) < v) __builtin_amdgcn_s_sleep(2);
    }
    __syncthreads();
    if (tid == 0) cstu(gl + (g << 5), v);
  }
  if (bid == DT0) {
    if (tid < 16) {
      while (cldu(gl + (tid << 5)) < v) __builtin_amdgcn_s_sleep(2);
    }
    __syncthreads();
    if (tid < 16) cstu(bc + (tid << 5), v);
  }
  if (tid == 0) {
    const int g = bid >> 4;
    while (cldu(bc + (g << 5)) < v) __builtin_amdgcn_s_sleep(2);
  }
  __atomic_signal_fence(__ATOMIC_SEQ_CST);
  __syncthreads();
}

// ---------------------------------------------------------------------------
// Tiled fp32 GEMM tile body.
// ---------------------------------------------------------------------------
__device__ void gemm_tile(const float* __restrict__ X, const float* __restrict__ Y,
                          float* __restrict__ Z, int M, int N, int Kd,
                          int mtile, int ntile) {
  __shared__ float Xs[16][65];
  __shared__ float Ys[16][65];
  const int tx = threadIdx.x & 15;
  const int ty = threadIdx.x >> 4;
  const int mbase = mtile * 64;
  const int nbase = ntile * 64;
  float acc[4][4] = {};
  for (int k0 = 0; k0 < Kd; k0 += 16) {
#pragma unroll
    for (int r = 0; r < 4; ++r) {
      int idx = threadIdx.x + 256 * r;
      int mm = idx >> 4, kk = idx & 15;
      int gm = mbase + mm, gk = k0 + kk;
      Xs[kk][mm] = (gm < M && gk < Kd) ? X[(size_t)gm * Kd + gk] : 0.f;
      int nn = idx & 63, k2 = idx >> 6;
      int gn = nbase + nn, gk2 = k0 + k2;
      Ys[k2][nn] = (gk2 < Kd && gn < N) ? Y[(size_t)gk2 * N + gn] : 0.f;
    }
    __syncthreads();
#pragma unroll
    for (int kk = 0; kk < 16; ++kk) {
      float xv[4], yv[4];
#pragma unroll
      for (int a = 0; a < 4; ++a) xv[a] = Xs[kk][ty * 4 + a];
#pragma unroll
      for (int b = 0; b < 4; ++b) yv[b] = Ys[kk][tx * 4 + b];
#pragma unroll
      for (int a = 0; a < 4; ++a)
#pragma unroll
        for (int b = 0; b < 4; ++b) acc[a][b] += xv[a] * yv[b];
    }
    __syncthreads();
  }
#pragma unroll
  for (int a = 0; a < 4; ++a) {
    int gm = mbase + ty * 4 + a;
    if (gm < M) {
#pragma unroll
      for (int b = 0; b < 4; ++b) {
        int gn = nbase + tx * 4 + b;
        if (gn < N) Z[(size_t)gm * N + gn] = acc[a][b];
      }
    }
  }
}

struct JobBatch {
  int n;
  int start[MAXJ + 1];
  int xsel[MAXJ], xoff[MAXJ], ysel[MAXJ], yoff[MAXJ], zoff[MAXJ];
  int M[MAXJ], N[MAXJ], K[MAXJ];
};

__global__ __launch_bounds__(256) void multi_gemm(JobBatch jb,
    const float* __restrict__ A, const float* __restrict__ Bm,
    const float* __restrict__ C, const float* __restrict__ Km,
    float* __restrict__ ws) {
  int b = blockIdx.x;
  int j = 0;
  while (j < jb.n - 1 && b >= jb.start[j + 1]) ++j;
  int rel = b - jb.start[j];
  const float* bases[5] = {ws, A, Bm, C, Km};
  const float* X = bases[jb.xsel[j]] + jb.xoff[j];
  const float* Y = bases[jb.ysel[j]] + jb.yoff[j];
  float* Z = ws + jb.zoff[j];
  int tn = jb.N[j] >> 6;
  gemm_tile(X, Y, Z, jb.M[j], jb.N[j], jb.K[j], rel / tn, rel % tn);
}

// ---------------------------------------------------------------------------
__global__ __launch_bounds__(256) void m2_kernel(const float* __restrict__ MT,
    const float* __restrict__ sm, float* __restrict__ M2g) {
  int idx = blockIdx.x * 256 + threadIdx.x;
  if (idx >= 128 * 32 * 256) return;
  int q = idx & 255;
  int ci = idx >> 8;
  const float* base = MT + (size_t)ci * 32 * 256 + q;
  float acc = 0.f;
#pragma unroll
  for (int j = 0; j < 32; ++j) acc += base[j * 256] * sm[j];
  M2g[idx] = acc;
}

__global__ __launch_bounds__(256) void wfir_kernel(const float* __restrict__ M2g,
    const float* __restrict__ Phi, float* __restrict__ W) {
  int idx = blockIdx.x * 256 + threadIdx.x;  // j*32768 + c*256 + q
  if (idx >= 64 * 32768) return;
  int j = idx >> 15;
  int cq = idx & 32767;
  int c = cq >> 8;
  int q = cq & 255;
  float acc = 0.f;
#pragma unroll
  for (int i = 0; i < 32; ++i)
    acc = fmaf(Phi[(i << 6) | j], M2g[(size_t)(((c << 5) | i) << 8) | q], acc);
  W[idx] = acc;
}

__global__ __launch_bounds__(256) void axpy_acl(const float* __restrict__ A,
    const float* __restrict__ BKC, float* __restrict__ Acl, float* __restrict__ P1) {
  int i = blockIdx.x * 256 + threadIdx.x;
  if (i < 262144) {
    float v = A[i] - BKC[i];
    Acl[i] = v;
    P1[i] = v;
  }
}

// ---------------------------------------------------------------------------
__global__ void init_kernel(const float* __restrict__ x0, float* __restrict__ xh,
    float* __restrict__ eh, float* __restrict__ ynh, float* __restrict__ uh0,
    float* __restrict__ dbnd, unsigned* __restrict__ arr,
    unsigned* __restrict__ gl, unsigned* __restrict__ bc) {
  int i = blockIdx.x * 256 + threadIdx.x;
  int stride = gridDim.x * 256;
  for (int k = i; k < 524288; k += stride) cst(xh + k, 0.f);
  for (int k = i; k < 139264; k += stride) cst(eh + k, 0.f);
  for (int k = i; k < 262144; k += stride) cst(ynh + k, 0.f);
  for (int k = i; k < 8192; k += stride) cst(uh0 + k, 0.f);
  for (int k = i; k < NWG * 32; k += stride) cstu(arr + k, 0u);
  for (int k = i; k < 16 * 32; k += stride) {
    cstu(gl + k, 0u);
    cstu(bc + k, 0u);
  }
  if (i < 512) cst(dbnd + i, x0[i]);
}

// ---------------------------------------------------------------------------
// Persistent main loop: 131 phases x ONE tree barrier. T=8*ph. Lag schedule
// identical to R12; all cross-WG data READS now via cached loads.
// ---------------------------------------------------------------------------
__global__ __launch_bounds__(TPB, 1) void main_kernel(
    const float* __restrict__ B, const float* __restrict__ C,
    const float* __restrict__ x0, const float* __restrict__ Wfir,
    const float* __restrict__ KC, const float* __restrict__ W0C,
    const float* __restrict__ Pp, const float* __restrict__ CAp,
    const float* __restrict__ W0CAp, const float* __restrict__ Rnp,
    const float* __restrict__ AB33p, const float* __restrict__ CAB33p,
    const float* __restrict__ W0CAB33p, const float* __restrict__ A8k,
    float* __restrict__ xh, float* __restrict__ uh0, float* __restrict__ eh,
    float* __restrict__ efir, float* __restrict__ ynh, float* __restrict__ dbnd,
    unsigned* __restrict__ arr, unsigned* __restrict__ gl,
    unsigned* __restrict__ bc) {
  __shared__ float smA[64 * 256];
  __shared__ float smV[512];
  __shared__ float smW[8 * 128];
  __shared__ float smVx[8 * 516];
  __shared__ float redsc[4][16];
  const int bid = blockIdx.x;
  const int tid = threadIdx.x;

  if (bid < SC_N) {
    // ================= SC (gather form) =================
    for (int i = tid; i < 16384; i += TPB) {
      int j = i >> 8;
      smA[i] = (j >= 1) ? Wfir[(size_t)j * 32768 + bid * 256 + (i & 255)] : 0.f;
    }
    __syncthreads();
    float ring[72];
#pragma unroll
    for (int k = 0; k < 72; ++k) ring[k] = 0.f;
    const int wv = tid >> 6;
    const int lane = tid & 63;
#pragma unroll 1
    for (int ph = 0; ph <= 130; ++ph) {
      if (ph >= 1 && ph < 129) {
        const int Ty = ph * 8 - 8;
#pragma unroll
        for (int k = 0; k < 64; ++k) ring[k] = ring[k + 8];
#pragma unroll
        for (int s = 0; s < 8; ++s)
          ring[64 + s] = ynh[(size_t)(Ty + s) * 256 + tid];
        float acc[8];
#pragma unroll
        for (int s = 0; s < 8; ++s) acc[s] = 0.f;
#pragma unroll
        for (int m = 1; m <= 63; ++m) {
          float w = smA[m * 256 + tid];
#pragma unroll
          for (int s = 0; s < 8; ++s) acc[s] = fmaf(w, ring[64 + s - m], acc[s]);
        }
#pragma unroll
        for (int s = 0; s < 8; ++s) {
          float v = acc[s];
          v += __shfl_xor(v, 32);
          v += __shfl_xor(v, 16);
          v += __shfl_xor(v, 8);
          v += __shfl_xor(v, 4);
          v += __shfl_xor(v, 2);
          v += __shfl_xor(v, 1);
          if (lane == 0) redsc[wv][s] = v;
        }
        __syncthreads();
        if (tid < 8) {
          float sum = redsc[0][tid] + redsc[1][tid] + redsc[2][tid] + redsc[3][tid];
          cst(efir + (size_t)(Ty + tid) * 128 + bid, sum);
        }
      }
      tree_barrier(arr, gl, bc, bid, tid, (unsigned)(ph + 1));
    }
  } else if (bid < YU0) {
    // ================= Yd =================
    const int r = bid - YD0;
    const int s = r >> 2;
    const int qtr = (r & 3) * 64;
    const int row = qtr + (tid >> 2);
    const int ks = (tid & 3) * 128;
    const float* Mrow = (s == 0) ? C : (CAp + (size_t)(s - 1) * 131072);
    const float4* m4 = (const float4*)(Mrow + (size_t)row * 512 + ks);
#pragma unroll 1
    for (int ph = 0; ph <= 130; ++ph) {
      if (ph < 128) {
        const int T = ph * 8;
        {
          float2 v = ld2(dbnd + (size_t)ph * 512 + 2 * tid);
          smV[2 * tid] = v.x;
          smV[2 * tid + 1] = v.y;
        }
        __syncthreads();
        const float4* v4 = (const float4*)(smV + ks);
        float a = 0.f;
#pragma unroll
        for (int it = 0; it < 32; ++it) {
          float4 mm = m4[it], vv = v4[it];
          a += mm.x * vv.x + mm.y * vv.y + mm.z * vv.z + mm.w * vv.w;
        }
        a += __shfl_down(a, 2);
        a += __shfl_down(a, 1);
        if ((tid & 3) == 0) atomicAdd(&ynh[(size_t)(T + s) * 256 + row], a);
      }
      tree_barrier(arr, gl, bc, bid, tid, (unsigned)(ph + 1));
    }
  } else if (bid < WD0) {
    // ================= Yu =================
    const int m = bid - YU0;
    const int row = tid;
    const float4* m4 = (const float4*)(CAB33p + (size_t)m * 32768 + (size_t)row * 128);
#pragma unroll 1
    for (int ph = 0; ph <= 130; ++ph) {
      if (ph < 128) {
        const int T = ph * 8;
        for (int i2 = tid; i2 < 512; i2 += TPB) {
          float2 v = ld2(uh0 + (size_t)(64 + T - 33) * 128 + 2 * i2);
          smW[2 * i2] = v.x;
          smW[2 * i2 + 1] = v.y;
        }
        __syncthreads();
        float acc[8];
#pragma unroll
        for (int s = 0; s < 8; ++s) acc[s] = 0.f;
#pragma unroll 4
        for (int it = 0; it < 32; ++it) {
          float4 mm = m4[it];
#pragma unroll
          for (int s = 0; s < 8; ++s) {
            if (s > m) {
              float4 vv = ((const float4*)(smW + (s - m - 1) * 128))[it];
              acc[s] += mm.x * vv.x + mm.y * vv.y + mm.z * vv.z + mm.w * vv.w;
            }
          }
        }
#pragma unroll
        for (int s = 0; s < 8; ++s)
          if (s > m) atomicAdd(&ynh[(size_t)(T + s) * 256 + row], acc[s]);
      }
      tree_barrier(arr, gl, bc, bid, tid, (unsigned)(ph + 1));
    }
  } else if (bid < WU0) {
    // ================= Wd =================
    const int s = bid - WD0;
    const int row = tid >> 1;
    const int seg = tid & 1;
    const float* Mrow = (s == 0) ? W0C : (W0CAp + (size_t)(s - 1) * 65536);
    const float4* m4 = (const float4*)(Mrow + (size_t)row * 512 + seg * 256);
#pragma unroll 1
    for (int ph = 0; ph <= 130; ++ph) {
      if (ph < 128) {
        const int T = ph * 8;
        {
          float2 v = ld2(dbnd + (size_t)ph * 512 + 2 * tid);
          smV[2 * tid] = v.x;
          smV[2 * tid + 1] = v.y;
        }
        __syncthreads();
        const float4* v4 = (const float4*)(smV + seg * 256);
        float a = 0.f;
#pragma unroll
        for (int it = 0; it < 64; ++it) {
          float4 mm = m4[it], vv = v4[it];
          a += mm.x * vv.x + mm.y * vv.y + mm.z * vv.z + mm.w * vv.w;
        }
        a += __shfl_down(a, 1);
        if (seg == 0) atomicAdd(&eh[(size_t)(T + s) * 128 + row], a);
      }
      tree_barrier(arr, gl, bc, bid, tid, (unsigned)(ph + 1));
    }
  } else if (bid < DT0) {
    // ================= Wu =================
    const int m = bid - WU0;
    const int row = tid >> 1;
    const int seg = tid & 1;
    const float4* m4 = (const float4*)(W0CAB33p + (size_t)m * 16384 + (size_t)row * 128 + seg * 64);
#pragma unroll 1
    for (int ph = 0; ph <= 130; ++ph) {
      if (ph < 128) {
        const int T = ph * 8;
        for (int i2 = tid; i2 < 512; i2 += TPB) {
          float2 v = ld2(uh0 + (size_t)(64 + T - 33) * 128 + 2 * i2);
          smW[2 * i2] = v.x;
          smW[2 * i2 + 1] = v.y;
        }
        __syncthreads();
        float acc[8];
#pragma unroll
        for (int s = 0; s < 8; ++s) acc[s] = 0.f;
#pragma unroll 4
        for (int it = 0; it < 16; ++it) {
          float4 mm = m4[it];
#pragma unroll
          for (int s = 0; s < 8; ++s) {
            if (s > m) {
              float4 vv = ((const float4*)(smW + (s - m - 1) * 128 + seg * 64))[it];
              acc[s] += mm.x * vv.x + mm.y * vv.y + mm.z * vv.z + mm.w * vv.w;
            }
          }
        }
#pragma unroll
        for (int s = 0; s < 8; ++s) {
          if (s > m) {
            float v = acc[s];
            v += __shfl_down(v, 1);
            if (seg == 0) atomicAdd(&eh[(size_t)(T + s) * 128 + row], v);
          }
        }
      }
      tree_barrier(arr, gl, bc, bid, tid, (unsigned)(ph + 1));
    }
  } else if (bid < XP0) {
    // ================= Dt ================= (+ barrier checker duty)
    const int g = bid - DT0;
    const int row = g * 32 + (tid >> 3);
    const int l8 = tid & 7;
#pragma unroll 1
    for (int ph = 0; ph <= 130; ++ph) {
      if (ph < 127) {
        const int T = ph * 8;
        {
          float2 v = ld2(dbnd + (size_t)ph * 512 + 2 * tid);
          smV[2 * tid] = v.x;
          smV[2 * tid + 1] = v.y;
        }
        for (int i2 = tid; i2 < 512; i2 += TPB) {
          float2 v = ld2(uh0 + (size_t)(64 + T - 33) * 128 + 2 * i2);
          smW[2 * i2] = v.x;
          smW[2 * i2 + 1] = v.y;
        }
        __syncthreads();
        float a = 0.f;
        {
          const float4* m4 = (const float4*)(A8k + (size_t)row * 512 + l8 * 64);
          const float4* v4 = (const float4*)(smV + l8 * 64);
#pragma unroll
          for (int it = 0; it < 16; ++it) {
            float4 mm = m4[it], vv = v4[it];
            a += mm.x * vv.x + mm.y * vv.y + mm.z * vv.z + mm.w * vv.w;
          }
        }
#pragma unroll
        for (int m = 0; m < 8; ++m) {
          const float4* m4 = (const float4*)(AB33p + (size_t)m * 65536 + (size_t)row * 128 + l8 * 16);
          const float4* v4 = (const float4*)(smW + (7 - m) * 128 + l8 * 16);
#pragma unroll
          for (int it = 0; it < 4; ++it) {
            float4 mm = m4[it], vv = v4[it];
            a += mm.x * vv.x + mm.y * vv.y + mm.z * vv.z + mm.w * vv.w;
          }
        }
        a += __shfl_down(a, 4);
        a += __shfl_down(a, 2);
        a += __shfl_down(a, 1);
        if (l8 == 0) cst(&dbnd[(size_t)(ph + 1) * 512 + row], a);
      }
      tree_barrier(arr, gl, bc, bid, tid, (unsigned)(ph + 1));
    }
  } else if (bid < XR0) {
    // ================= Xp =================
    const int r = bid - XP0;
    const int s = r >> 2;
    const int qtr = (r & 3) << 7;
    const int row = qtr + (tid >> 1);
    const int seg = tid & 1;
#pragma unroll 1
    for (int ph = 0; ph <= 130; ++ph) {
      if (ph >= 2 && ph < 130) {
        const int Tq = ph * 8 - 16;
        {
          const float* src = (ph == 2) ? x0 : (xh + (size_t)(Tq - 1) * 512);
          float2 v = ld2(src + 2 * tid);
          smV[2 * tid] = v.x;
          smV[2 * tid + 1] = v.y;
        }
        __syncthreads();
        const int pslot = (ph == 2) ? s : (s + 1);
        if (pslot == 0) {
          if (seg == 0) atomicAdd(&xh[(size_t)Tq * 512 + row], smV[row]);
        } else {
          const float4* m4 = (const float4*)(Pp + (size_t)(pslot - 1) * 262144 +
                                             (size_t)row * 512 + seg * 256);
          const float4* v4 = (const float4*)(smV + seg * 256);
          float a = 0.f;
#pragma unroll
          for (int it = 0; it < 64; ++it) {
            float4 mm = m4[it], vv = v4[it];
            a += mm.x * vv.x + mm.y * vv.y + mm.z * vv.z + mm.w * vv.w;
          }
          a += __shfl_down(a, 1);
          if (seg == 0) atomicAdd(&xh[(size_t)(Tq + s) * 512 + row], a);
        }
      }
      tree_barrier(arr, gl, bc, bid, tid, (unsigned)(ph + 1));
    }
  } else if (bid < U0) {
    // ================= Xr =================
    const int r = bid - XR0;
    const int i = r >> 1;
    const int half = (r & 1) << 8;
    const int row = half + tid;
    const float* Rrow = (i == 0) ? (B + (size_t)row * 128)
                                 : (Rnp + (size_t)(i - 1) * 65536 + (size_t)row * 128);
    const float4* m4 = (const float4*)Rrow;
#pragma unroll 1
    for (int ph = 0; ph <= 130; ++ph) {
      if (ph >= 2 && ph < 130) {
        const int Tq = ph * 8 - 16;
        for (int i2 = tid; i2 < 512; i2 += TPB) {
          int idx = 2 * i2;
          float2 v;
          if (ph == 2 && idx < 128) {
            v.x = 0.f;
            v.y = 0.f;
          } else {
            float2 a2 = ld2(eh + (size_t)(Tq - 1) * 128 + idx);
            float2 b2 = ld2(efir + (size_t)(Tq - 1) * 128 + idx);
            v.x = a2.x + b2.x;
            v.y = a2.y + b2.y;
          }
          smW[idx] = v.x;
          smW[idx + 1] = v.y;
        }
        __syncthreads();
        float acc[8];
#pragma unroll
        for (int s = 0; s < 8; ++s) acc[s] = 0.f;
#pragma unroll 4
        for (int it = 0; it < 32; ++it) {
          float4 mm = m4[it];
#pragma unroll
          for (int s = 0; s < 8; ++s) {
            if (s >= i) {
              float4 vv = ((const float4*)(smW + (s - i) * 128))[it];
              acc[s] += mm.x * vv.x + mm.y * vv.y + mm.z * vv.z + mm.w * vv.w;
            }
          }
        }
#pragma unroll
        for (int s = 0; s < 8; ++s)
          if (s >= i) atomicAdd(&xh[(size_t)(Tq + s) * 512 + row], acc[s]);
      }
      tree_barrier(arr, gl, bc, bid, tid, (unsigned)(ph + 1));
    }
  } else {
    // ================= U =================
    const int g = bid - U0;
    const int o = tid >> 1;
    const int par = tid & 1;
    const int s = o >> 4;
    const int lr = o & 15;
    const int row = g * 16 + lr;
    const float4* m4 = (const float4*)(KC + (size_t)row * 512 + par * 256);
#pragma unroll 1
    for (int ph = 0; ph <= 130; ++ph) {
      if (ph >= 3) {
        const int Tu = ph * 8 - 24;
        for (int i2 = tid; i2 < 2048; i2 += TPB) {
          int idx = 2 * i2;
          int rr = idx >> 9;
          int cc = idx & 511;
          float2 v = ld2(xh + (size_t)(Tu + rr) * 512 + cc);
          smVx[rr * 516 + cc] = v.x;
          smVx[rr * 516 + cc + 1] = v.y;
        }
        __syncthreads();
        const float4* v4 = (const float4*)(smVx + s * 516 + par * 256);
        float a = 0.f;
#pragma unroll
        for (int it = 0; it < 64; ++it) {
          float4 mm = m4[it], vv = v4[it];
          a += mm.x * vv.x + mm.y * vv.y + mm.z * vv.z + mm.w * vv.w;
        }
        a += __shfl_down(a, 1);
        if (par == 0) {
          float u = eh[(size_t)(Tu + s) * 128 + row] +
                    efir[(size_t)(Tu + s) * 128 + row] - a;
          cst(&uh0[(size_t)(64 + Tu + s) * 128 + row], u);
        }
      }
      tree_barrier(arr, gl, bc, bid, tid, (unsigned)(ph + 1));
    }
  }
}

// ---------------------------------------------------------------------------
// Epilogue: y_obs_t = C x_t; cost_t = y'Q y + u'R u.  (one WG per t)
// Runs in a separate dispatch (kernel boundary = full coherence), so plain
// cached loads are safe here too.
// ---------------------------------------------------------------------------
__global__ __launch_bounds__(256) void cost_kernel(const float* __restrict__ C,
    const float* __restrict__ Q, const float* __restrict__ R,
    const float* __restrict__ xh, const float* __restrict__ uh0,
    float* __restrict__ out) {
  __shared__ float xs[512];
  __shared__ float ys[256];
  __shared__ float us[128];
  __shared__ float redw[4];
  const int t = blockIdx.x;
  const int tid = threadIdx.x;
  {
    float2 v = ld2(xh + (size_t)t * 512 + 2 * tid);
    xs[2 * tid] = v.x;
    xs[2 * tid + 1] = v.y;
  }
  if (tid < 64) {
    float2 v = ld2(uh0 + (size_t)(64 + t) * 128 + 2 * tid);
    us[2 * tid] = v.x;
    us[2 * tid + 1] = v.y;
  }
  __syncthreads();
  {
    const float4* m4 = (const float4*)(C + (size_t)tid * 512);
    const float4* v4 = (const float4*)xs;
    float a = 0.f;
    for (int it = 0; it < 128; ++it) {
      float4 mm = m4[it], vv = v4[it];
      a += mm.x * vv.x + mm.y * vv.y + mm.z * vv.z + mm.w * vv.w;
    }
    ys[tid] = a;
  }
  __syncthreads();
  float acc;
  {
    const float* Qr = Q + (size_t)tid * 256;
    float qy = 0.f;
    for (int k = 0; k < 256; ++k) qy = fmaf(Qr[k], ys[k], qy);
    acc = qy * ys[tid];
  }
  if (tid < 128) {
    const float* Rr = R + (size_t)tid * 128;
    float ru = 0.f;
    for (int k = 0; k < 128; ++k) ru = fmaf(Rr[k], us[k], ru);
    acc += ru * us[tid];
  }
  float v = acc;
  v += __shfl_xor(v, 32);
  v += __shfl_xor(v, 16);
  v += __shfl_xor(v, 8);
  v += __shfl_xor(v, 4);
  v += __shfl_xor(v, 2);
  v += __shfl_xor(v, 1);
  if ((tid & 63) == 0) redw[tid >> 6] = v;
  __syncthreads();
  if (tid == 0) out[t] = redw[0] + redw[1] + redw[2] + redw[3];
}

// ---------------------------------------------------------------------------
extern "C" void kernel_launch(void* const* d_in, const int* in_sizes, int n_in,
                              void* d_out, int out_size, void* d_ws, size_t ws_size,
                              hipStream_t stream) {
  (void)in_sizes; (void)n_in; (void)out_size; (void)ws_size;
  const float* A = (const float*)d_in[0];
  const float* B = (const float*)d_in[1];
  const float* C = (const float*)d_in[2];
  const float* Q = (const float*)d_in[3];
  const float* R = (const float*)d_in[4];
  const float* Km = (const float*)d_in[5];
  const float* MT = (const float*)d_in[6];
  const float* Phi = (const float*)d_in[7];
  const float* sm = (const float*)d_in[8];
  const float* x0 = (const float*)d_in[9];

  float* ws = (float*)d_ws;
  const int oWfir = 0;
  const int oKC = 2097152;
  const int oW0C = 2162688;
  const int oAcl = 2228224;
  const int oP = 2490368;            // 8 x 262144  (P[1..8])
  const int oCA = 4587520;           // 7 x 131072  (CA[1..7])
  const int oW0CA = 5505024;         // 7 x 65536   (W0CA[1..7])
  const int oRn = 5963776;           // 7 x 65536   (Rn[1..7])
  const int oApB = 6422528;          // 8 x 65536   (ApB[1..8])
  const int oAB33 = 6946816;         // 8 x 65536   (AB33[0..7])
  const int oCAB33 = 7471104;        // 7 x 32768
  const int oW0CAB33 = 7700480;      // 7 x 16384
  const int oA2 = 7815168;
  const int oA4 = 8077312;
  const int oA8 = 8339456;
  const int oA16 = 8601600;
  const int oA32 = 8863744;
  const int oM2 = 9125888;
  const int oBKC = oM2;
  const int oxh = 10174464;
  const int ouh0 = 10698752;
  const int oeh = 10838016;
  const int oynh = 10977280;
  const int odbnd = 11239424;
  const int oefir = 11306496;        // 1024x128 = 131072
  const int oarr = 11437568;         // NWG*32
  const int ogl = oarr + NWG * 32;   // 16*32
  const int obc = ogl + 512;         // 16*32

  float* xh = ws + oxh;
  float* uh0 = ws + ouh0;
  float* eh = ws + oeh;
  float* ynh = ws + oynh;
  float* dbnd = ws + odbnd;
  float* efir = ws + oefir;
  unsigned* arr = (unsigned*)(ws + oarr);
  unsigned* gl = (unsigned*)(ws + ogl);
  unsigned* bc = (unsigned*)(ws + obc);

  JobBatch jb;
  jb.n = 0;
  jb.start[0] = 0;
  auto J = [&](int xs_, int xo, int ys_, int yo, int zo, int M, int N, int K) {
    int i = jb.n++;
    jb.xsel[i] = xs_; jb.xoff[i] = xo; jb.ysel[i] = ys_; jb.yoff[i] = yo;
    jb.zoff[i] = zo; jb.M[i] = M; jb.N[i] = N; jb.K[i] = K;
    jb.start[i + 1] = jb.start[i] + (M >> 6) * (N >> 6);
  };
  auto L = [&]() {
    multi_gemm<<<dim3(jb.start[jb.n]), dim3(256), 0, stream>>>(jb, A, B, C, Km, ws);
    jb.n = 0;
    jb.start[0] = 0;
  };

  init_kernel<<<dim3(2048), dim3(256), 0, stream>>>(x0, xh, eh, ynh, uh0, dbnd,
                                                    arr, gl, bc);
  m2_kernel<<<dim3(4096), dim3(256), 0, stream>>>(MT, sm, ws + oM2);
  wfir_kernel<<<dim3(8192), dim3(256), 0, stream>>>(ws + oM2, Phi, ws + oWfir);

  // ---- L1 ----
  J(4, 0, 3, 0, oKC, 128, 512, 256);
  J(1, 0, 1, 0, oA2, 512, 512, 512);
  J(1, 0, 2, 0, oApB, 512, 128, 512);
  J(3, 0, 1, 0, oCA, 256, 512, 512);
  L();
  // ---- L2 ----
  J(2, 0, 0, oKC, oBKC, 512, 512, 128);
  J(0, oA2, 0, oA2, oA4, 512, 512, 512);
  J(0, oCA, 1, 0, oCA + 131072, 256, 512, 512);
  J(1, 0, 0, oApB, oApB + 65536, 512, 128, 512);
  J(0, oWfir, 3, 0, oW0C, 128, 512, 256);
  L();
  axpy_acl<<<dim3(1024), dim3(256), 0, stream>>>(A, ws + oBKC, ws + oAcl, ws + oP);
  // ---- L3 ----
  J(0, oA4, 0, oA4, oA8, 512, 512, 512);
  J(0, oP, 0, oP, oP + 262144, 512, 512, 512);
  J(0, oCA, 0, oA2, oCA + 2 * 131072, 256, 512, 512);
  J(0, oCA + 131072, 0, oA2, oCA + 3 * 131072, 256, 512, 512);
  J(0, oW0C, 1, 0, oW0CA, 128, 512, 512);
  J(0, oW0C, 0, oA2, oW0CA + 65536, 128, 512, 512);
  J(0, oA2, 0, oApB, oApB + 2 * 65536, 512, 128, 512);
  J(0, oA2, 0, oApB + 65536, oApB + 3 * 65536, 512, 128, 512);
  L();
  // ---- L4 ----
  J(0, oA8, 0, oA8, oA16, 512, 512, 512);
  J(0, oP, 0, oP + 262144, oP + 2 * 262144, 512, 512, 512);
  J(0, oP + 262144, 0, oP + 262144, oP + 3 * 262144, 512, 512, 512);
  for (int i = 1; i <= 3; ++i)
    J(0, oCA + (i - 1) * 131072, 0, oA4, oCA + (i + 3) * 131072, 256, 512, 512);
  for (int i = 1; i <= 2; ++i)
    J(0, oW0CA + (i - 1) * 65536, 0, oA2, oW0CA + (i + 1) * 65536, 128, 512, 512);
  for (int k = 1; k <= 4; ++k)
    J(0, oA4, 0, oApB + (k - 1) * 65536, oApB + (k + 3) * 65536, 512, 128, 512);
  J(0, oP, 2, 0, oRn, 512, 128, 512);
  J(0, oP + 262144, 2, 0, oRn + 65536, 512, 128, 512);
  L();
  // ---- L5 ----
  J(0, oA16, 0, oA16, oA32, 512, 512, 512);
  for (int i = 1; i <= 4; ++i)
    J(0, oP + (i - 1) * 262144, 0, oP + 3 * 262144, oP + (i + 3) * 262144, 512, 512, 512);
  for (int i = 1; i <= 3; ++i)
    J(0, oW0CA + (i - 1) * 65536, 0, oA4, oW0CA + (i + 3) * 65536, 128, 512, 512);
  J(0, oP + 2 * 262144, 2, 0, oRn + 2 * 65536, 512, 128, 512);
  J(0, oP + 3 * 262144, 2, 0, oRn + 3 * 65536, 512, 128, 512);
  L();
  // ---- L6 ----
  for (int m = 0; m <= 7; ++m)
    J(0, oA32, 0, oApB + m * 65536, oAB33 + m * 65536, 512, 128, 512);
  for (int i = 5; i <= 7; ++i)
    J(0, oP + (i - 1) * 262144, 2, 0, oRn + (i - 1) * 65536, 512, 128, 512);
  L();
  // ---- L7 ----
  for (int m = 0; m <= 6; ++m)
    J(3, 0, 0, oAB33 + m * 65536, oCAB33 + m * 32768, 256, 128, 512);
  for (int m = 0; m <= 6; ++m)
    J(0, oW0C, 0, oAB33 + m * 65536, oW0CAB33 + m * 16384, 128, 128, 512);
  L();

  main_kernel<<<dim3(NWG), dim3(TPB), 0, stream>>>(
      B, C, x0, ws + oWfir, ws + oKC, ws + oW0C, ws + oP, ws + oCA,
      ws + oW0CA, ws + oRn, ws + oAB33, ws + oCAB33, ws + oW0CAB33,
      ws + oA8, xh, uh0, eh, efir, ynh, dbnd, arr, gl, bc);

  cost_kernel<<<dim3(1024), dim3(256), 0, stream>>>(C, Q, R, xh, uh0,
                                                    (float*)d_out);
}